// Round 1
// baseline (1655.831 us; speedup 1.0000x reference)
//
#include <hip/hip_runtime.h>
#include <hip/hip_bf16.h>

#define BB 2
#define HH 56
#define WW 56
#define LL (HH*WW)          // 3136
#define DM 96
#define DI 192
#define NS 16               // d_state
#define DTR 6
#define KK 4
#define CDBL (DTR + 2*NS)   // 38

// ---------------- kernel 1: in_proj (x @ W^T), split xc / silu(z) ----------------
__global__ __launch_bounds__(384) void k_inproj(const float* __restrict__ x,
                                                const float* __restrict__ w,
                                                float* __restrict__ xcpre,
                                                float* __restrict__ zsilu) {
    int bl = blockIdx.x;           // b*L + l (spatial)
    int t = threadIdx.x;           // 0..383 output channel e
    __shared__ float xr[DM];
    if (t < DM) xr[t] = x[bl*DM + t];
    __syncthreads();
    float acc = 0.f;
    const float* wr = w + t*DM;
    #pragma unroll
    for (int i = 0; i < DM; ++i) acc = fmaf(wr[i], xr[i], acc);
    if (t < DI) {
        xcpre[bl*DI + t] = acc;
    } else {
        float s = acc / (1.f + expf(-acc));   // silu
        zsilu[bl*DI + (t - DI)] = s;
    }
}

// ------------- kernel 2: depthwise 3x3 conv + bias + silu + scan scatter -------------
__global__ __launch_bounds__(DI) void k_conv(const float* __restrict__ xcpre,
                                             const float* __restrict__ cw,
                                             const float* __restrict__ cb,
                                             float* __restrict__ xs0,
                                             float* __restrict__ xs1) {
    int bl = blockIdx.x;
    int b = bl / LL, l = bl % LL;
    int h = l / WW, w = l % WW;
    int c = threadIdx.x;
    float acc = cb[c];
    #pragma unroll
    for (int dh = -1; dh <= 1; ++dh) {
        int hh = h + dh;
        if (hh < 0 || hh >= HH) continue;
        #pragma unroll
        for (int dw = -1; dw <= 1; ++dw) {
            int ww2 = w + dw;
            if (ww2 < 0 || ww2 >= WW) continue;
            acc = fmaf(xcpre[(b*LL + hh*WW + ww2)*DI + c],
                       cw[c*9 + (dh+1)*3 + (dw+1)], acc);
        }
    }
    float v = acc / (1.f + expf(-acc));   // silu
    // scan permutations (involutions): spatial (h,w) -> stream positions
    int i  = (w & 1) ? (HH-1-h) : h;
    int l0 = i*WW + w;                       // stream 0 (hscan, row-major)
    int l1 = ((i & 1) ? (WW-1-w) : w)*HH + i; // stream 1 (vscan after hscan)
    xs0[(b*LL + l0)*DI + c] = v;
    xs1[(b*LL + l1)*DI + c] = v;
}

// ------------- kernel 3: x_proj (38x192) + dt_proj (192x6) + softplus -------------
#define TL 32
__global__ __launch_bounds__(256) void k_proj(const float* __restrict__ xs0,
                                              const float* __restrict__ xs1,
                                              const float* __restrict__ xpw,   // (K,38,192)
                                              const float* __restrict__ dtw,   // (K,192,6)
                                              const float* __restrict__ dtb,   // (K,192)
                                              float* __restrict__ delta,       // (B,K,L,192)
                                              float* __restrict__ Bsb,         // (B,K,L,16)
                                              float* __restrict__ Csb) {       // (B,K,L,16)
    int tile = blockIdx.x, k = blockIdx.y, b = blockIdx.z;
    int t = threadIdx.x;
    __shared__ float Wl[CDBL*DI];      // 38*192
    __shared__ float dtWl[DI*DTR];     // 192*6
    __shared__ float dtbl[DI];
    __shared__ float Xl[TL*193];       // padded stride 193
    __shared__ float dblL[DTR*33];     // dt rows, padded

    for (int idx = t; idx < CDBL*DI; idx += 256) Wl[idx] = xpw[k*CDBL*DI + idx];
    for (int idx = t; idx < DI*DTR;  idx += 256) dtWl[idx] = dtw[k*DI*DTR + idx];
    if (t < DI) dtbl[t] = dtb[k*DI + t];
    const float* src = (k & 1) ? xs1 : xs0;
    for (int idx = t; idx < TL*DI; idx += 256) {
        int ll = idx / DI, i = idx % DI;
        int lg = tile*TL + ll;
        int lp = (k >= 2) ? (LL-1-lg) : lg;
        Xl[ll*193 + i] = src[(b*LL + lp)*DI + i];
    }
    __syncthreads();

    // phase 1: x_dbl = W_k @ x  (38 outputs per l)
    for (int idx = t; idx < CDBL*TL; idx += 256) {
        int c = idx >> 5, ll = idx & 31;
        float acc = 0.f;
        #pragma unroll 8
        for (int i = 0; i < DI; ++i) acc = fmaf(Wl[c*DI + i], Xl[ll*193 + i], acc);
        int lg = tile*TL + ll;
        if (c < DTR) {
            dblL[c*33 + ll] = acc;
        } else if (c < DTR + NS) {
            Bsb[((b*KK + k)*LL + lg)*NS + (c - DTR)] = acc;
        } else {
            Csb[((b*KK + k)*LL + lg)*NS + (c - DTR - NS)] = acc;
        }
    }
    __syncthreads();

    // phase 2: delta = softplus(dt_w @ dts + bias)
    for (int idx = t; idx < DI*TL; idx += 256) {
        int d = idx % DI, ll = idx / DI;
        float acc = dtbl[d];
        #pragma unroll
        for (int r = 0; r < DTR; ++r) acc = fmaf(dtWl[d*DTR + r], dblL[r*33 + ll], acc);
        float sp = fmaxf(acc, 0.f) + log1pf(expf(-fabsf(acc)));
        delta[((b*KK + k)*LL + tile*TL + ll)*DI + d] = sp;
    }
}

// ------------- kernel 4: selective scan (sequential over L) -------------
// block = 64 threads = 4 d-channels x 16 states; grid = (48, K, B)
__global__ __launch_bounds__(64) void k_scan(const float* __restrict__ delta,
                                             const float* __restrict__ xs0,
                                             const float* __restrict__ xs1,
                                             const float* __restrict__ Bsb,
                                             const float* __restrict__ Csb,
                                             const float* __restrict__ A_logs, // (K*192,16)
                                             const float* __restrict__ Ds,     // (K*192,)
                                             float* __restrict__ oy) {         // (B,K,L,192)
    int b = blockIdx.z, k = blockIdx.y;
    int t = threadIdx.x;
    int d = blockIdx.x*4 + (t >> 4);
    int n = t & 15;
    int kd = k*DI + d;
    const float A  = -expf(A_logs[kd*NS + n]);
    const float Dv = Ds[kd];
    const bool rev = (k >= 2);
    const float* src = (k & 1) ? xs1 : xs0;
    const float* dptr = delta + (size_t)((b*KK + k))*LL*DI + d;
    const float* bptr = Bsb   + (size_t)((b*KK + k))*LL*NS + n;
    const float* cptr = Csb   + (size_t)((b*KK + k))*LL*NS + n;
    float*       yptr = oy    + (size_t)((b*KK + k))*LL*DI + d;
    const float* up   = src + (size_t)b*LL*DI + d + (rev ? (size_t)(LL-1)*DI : 0);
    const int ustep = rev ? -DI : DI;

    float h = 0.f;
    #pragma unroll 4
    for (int l = 0; l < LL; ++l) {
        float dt = dptr[l*DI];
        float u  = up[l*ustep];
        float Bn = bptr[l*NS];
        float Cn = cptr[l*NS];
        float dA = __expf(dt * A);
        h = fmaf(dA, h, dt * Bn * u);
        float py = h * Cn;
        py += __shfl_xor(py, 1);
        py += __shfl_xor(py, 2);
        py += __shfl_xor(py, 4);
        py += __shfl_xor(py, 8);
        if (n == 0) yptr[l*DI] = fmaf(u, Dv, py);
    }
}

// ------------- kernel 5: gather 4 streams + LayerNorm + silu gate + out_proj -------------
__global__ __launch_bounds__(DI) void k_out(const float* __restrict__ oy,
                                            const float* __restrict__ zsilu,
                                            const float* __restrict__ onw,
                                            const float* __restrict__ onb,
                                            const float* __restrict__ opw,   // (96,192)
                                            float* __restrict__ out) {
    int bl = blockIdx.x;
    int b = bl / LL, l = bl % LL;
    int h = l / WW, w = l % WW;
    int i  = (w & 1) ? (HH-1-h) : h;
    int l0 = i*WW + w;
    int l1 = ((i & 1) ? (WW-1-w) : w)*HH + i;
    int t = threadIdx.x;
    size_t base = (size_t)b*KK*LL*DI;
    float yd = oy[base + (size_t)(0*LL + l0)*DI + t]
             + oy[base + (size_t)(1*LL + l1)*DI + t]
             + oy[base + (size_t)(2*LL + (LL-1-l0))*DI + t]
             + oy[base + (size_t)(3*LL + (LL-1-l1))*DI + t];

    __shared__ float red[8];
    __shared__ float yv[DI];
    float s1 = yd, s2 = yd*yd;
    #pragma unroll
    for (int m = 1; m < 64; m <<= 1) { s1 += __shfl_xor(s1, m); s2 += __shfl_xor(s2, m); }
    int wave = t >> 6;
    if ((t & 63) == 0) { red[wave] = s1; red[4 + wave] = s2; }
    __syncthreads();
    float tot1 = red[0] + red[1] + red[2];
    float tot2 = red[4] + red[5] + red[6];
    float mu  = tot1 / DI;
    float var = tot2 / DI - mu*mu;
    float ry  = rsqrtf(var + 1e-5f);
    float yn  = (yd - mu) * ry * onw[t] + onb[t];
    yv[t] = yn * zsilu[(size_t)bl*DI + t];
    __syncthreads();
    if (t < DM) {
        float acc = 0.f;
        const float* wr = opw + t*DI;
        #pragma unroll 8
        for (int i2 = 0; i2 < DI; ++i2) acc = fmaf(wr[i2], yv[i2], acc);
        out[(size_t)bl*DM + t] = acc;
    }
}

extern "C" void kernel_launch(void* const* d_in, const int* in_sizes, int n_in,
                              void* d_out, int out_size, void* d_ws, size_t ws_size,
                              hipStream_t stream) {
    const float* x      = (const float*)d_in[0];
    const float* ipw    = (const float*)d_in[1];
    const float* convw  = (const float*)d_in[2];
    const float* convb  = (const float*)d_in[3];
    const float* xpw    = (const float*)d_in[4];
    const float* dtw    = (const float*)d_in[5];
    const float* dtb    = (const float*)d_in[6];
    const float* A_logs = (const float*)d_in[7];
    const float* Ds     = (const float*)d_in[8];
    const float* onw    = (const float*)d_in[9];
    const float* onb    = (const float*)d_in[10];
    const float* opw    = (const float*)d_in[11];
    float* out = (float*)d_out;

    float* ws = (float*)d_ws;
    const size_t SZ_BLD  = (size_t)BB*LL*DI;      // 1,204,224
    const size_t SZ_BKLD = (size_t)BB*KK*LL*DI;   // 4,816,896
    const size_t SZ_BKLN = (size_t)BB*KK*LL*NS;   //   401,408
    float* xcpre = ws;
    float* zsilu = xcpre + SZ_BLD;
    float* xs0   = zsilu + SZ_BLD;
    float* xs1   = xs0   + SZ_BLD;
    float* delta = xs1   + SZ_BLD;
    float* Bsb   = delta + SZ_BKLD;
    float* Csb   = Bsb   + SZ_BKLN;
    float* oy    = Csb   + SZ_BKLN;

    k_inproj<<<BB*LL, 384, 0, stream>>>(x, ipw, xcpre, zsilu);
    k_conv<<<BB*LL, DI, 0, stream>>>(xcpre, convw, convb, xs0, xs1);
    dim3 g3(LL/TL, KK, BB);
    k_proj<<<g3, 256, 0, stream>>>(xs0, xs1, xpw, dtw, dtb, delta, Bsb, Csb);
    dim3 g4(DI/4, KK, BB);
    k_scan<<<g4, 64, 0, stream>>>(delta, xs0, xs1, Bsb, Csb, A_logs, Ds, oy);
    k_out<<<BB*LL, DI, 0, stream>>>(oy, zsilu, onw, onb, opw, out);
}

// Round 2
// 470.842 us; speedup vs baseline: 3.5167x; 3.5167x over previous
//
#include <hip/hip_runtime.h>
#include <hip/hip_bf16.h>

#define BB 2
#define HH 56
#define WW 56
#define LL (HH*WW)          // 3136
#define DM 96
#define DI 192
#define NS 16               // d_state
#define DTR 6
#define KK 4
#define CDBL (DTR + 2*NS)   // 38
#define CS 64               // scan chunk size
#define NC 49               // number of chunks (CS*NC == LL)

// ---------------- kernel 1: in_proj (x @ W^T), split xc / silu(z) ----------------
__global__ __launch_bounds__(384) void k_inproj(const float* __restrict__ x,
                                                const float* __restrict__ w,
                                                float* __restrict__ xcpre,
                                                float* __restrict__ zsilu) {
    int bl = blockIdx.x;           // b*L + l (spatial)
    int t = threadIdx.x;           // 0..383 output channel e
    __shared__ float xr[DM];
    if (t < DM) xr[t] = x[bl*DM + t];
    __syncthreads();
    float acc = 0.f;
    const float* wr = w + t*DM;
    #pragma unroll
    for (int i = 0; i < DM; ++i) acc = fmaf(wr[i], xr[i], acc);
    if (t < DI) {
        xcpre[bl*DI + t] = acc;
    } else {
        float s = acc / (1.f + expf(-acc));   // silu
        zsilu[bl*DI + (t - DI)] = s;
    }
}

// ------------- kernel 2: depthwise 3x3 conv + bias + silu + scan scatter -------------
__global__ __launch_bounds__(DI) void k_conv(const float* __restrict__ xcpre,
                                             const float* __restrict__ cw,
                                             const float* __restrict__ cb,
                                             float* __restrict__ xs0,
                                             float* __restrict__ xs1) {
    int bl = blockIdx.x;
    int b = bl / LL, l = bl % LL;
    int h = l / WW, w = l % WW;
    int c = threadIdx.x;
    float acc = cb[c];
    #pragma unroll
    for (int dh = -1; dh <= 1; ++dh) {
        int hh = h + dh;
        if (hh < 0 || hh >= HH) continue;
        #pragma unroll
        for (int dw = -1; dw <= 1; ++dw) {
            int ww2 = w + dw;
            if (ww2 < 0 || ww2 >= WW) continue;
            acc = fmaf(xcpre[(b*LL + hh*WW + ww2)*DI + c],
                       cw[c*9 + (dh+1)*3 + (dw+1)], acc);
        }
    }
    float v = acc / (1.f + expf(-acc));   // silu
    // scan permutations (involutions): spatial (h,w) -> stream positions
    int i  = (w & 1) ? (HH-1-h) : h;
    int l0 = i*WW + w;                       // stream 0 (hscan, row-major)
    int l1 = ((i & 1) ? (WW-1-w) : w)*HH + i; // stream 1 (vscan after hscan)
    xs0[(b*LL + l0)*DI + c] = v;
    xs1[(b*LL + l1)*DI + c] = v;
}

// ------------- kernel 3: x_proj (38x192) + dt_proj (192x6) + softplus -------------
#define TL 32
__global__ __launch_bounds__(256) void k_proj(const float* __restrict__ xs0,
                                              const float* __restrict__ xs1,
                                              const float* __restrict__ xpw,   // (K,38,192)
                                              const float* __restrict__ dtw,   // (K,192,6)
                                              const float* __restrict__ dtb,   // (K,192)
                                              float* __restrict__ delta,       // (B,K,L,192)
                                              float* __restrict__ Bsb,         // (B,K,L,16)
                                              float* __restrict__ Csb) {       // (B,K,L,16)
    int tile = blockIdx.x, k = blockIdx.y, b = blockIdx.z;
    int t = threadIdx.x;
    __shared__ float Wl[CDBL*DI];      // 38*192
    __shared__ float dtWl[DI*DTR];     // 192*6
    __shared__ float dtbl[DI];
    __shared__ float Xl[TL*193];       // padded stride 193
    __shared__ float dblL[DTR*33];     // dt rows, padded

    for (int idx = t; idx < CDBL*DI; idx += 256) Wl[idx] = xpw[k*CDBL*DI + idx];
    for (int idx = t; idx < DI*DTR;  idx += 256) dtWl[idx] = dtw[k*DI*DTR + idx];
    if (t < DI) dtbl[t] = dtb[k*DI + t];
    const float* src = (k & 1) ? xs1 : xs0;
    for (int idx = t; idx < TL*DI; idx += 256) {
        int ll = idx / DI, i = idx % DI;
        int lg = tile*TL + ll;
        int lp = (k >= 2) ? (LL-1-lg) : lg;
        Xl[ll*193 + i] = src[(b*LL + lp)*DI + i];
    }
    __syncthreads();

    // phase 1: x_dbl = W_k @ x  (38 outputs per l)
    for (int idx = t; idx < CDBL*TL; idx += 256) {
        int c = idx >> 5, ll = idx & 31;
        float acc = 0.f;
        #pragma unroll 8
        for (int i = 0; i < DI; ++i) acc = fmaf(Wl[c*DI + i], Xl[ll*193 + i], acc);
        int lg = tile*TL + ll;
        if (c < DTR) {
            dblL[c*33 + ll] = acc;
        } else if (c < DTR + NS) {
            Bsb[((b*KK + k)*LL + lg)*NS + (c - DTR)] = acc;
        } else {
            Csb[((b*KK + k)*LL + lg)*NS + (c - DTR - NS)] = acc;
        }
    }
    __syncthreads();

    // phase 2: delta = softplus(dt_w @ dts + bias)
    for (int idx = t; idx < DI*TL; idx += 256) {
        int d = idx % DI, ll = idx / DI;
        float acc = dtbl[d];
        #pragma unroll
        for (int r = 0; r < DTR; ++r) acc = fmaf(dtWl[d*DTR + r], dblL[r*33 + ll], acc);
        float sp = fmaxf(acc, 0.f) + log1pf(expf(-fabsf(acc)));
        delta[((b*KK + k)*LL + tile*TL + ll)*DI + d] = sp;
    }
}

// ------------- kernel 4a: chunked scan pass 1 — per-chunk local scan -------------
// block = 64 threads = 4 d-channels x 16 states; grid = (48, NC, B*K)
__global__ __launch_bounds__(64) void k_scan1(const float* __restrict__ delta,
                                              const float* __restrict__ xs0,
                                              const float* __restrict__ xs1,
                                              const float* __restrict__ Bsb,
                                              const float* __restrict__ A_logs,
                                              float* __restrict__ P,     // (B*K*DI*NS, NC)
                                              float* __restrict__ Hend) {
    int bk = blockIdx.z;
    int k = bk & 3, b = bk >> 2;
    int c = blockIdx.y;
    int t = threadIdx.x;
    int d = blockIdx.x*4 + (t >> 4);
    int n = t & 15;
    int kd = k*DI + d;
    const float A = -expf(A_logs[kd*NS + n]);
    const bool rev = (k >= 2);
    const float* src = (k & 1) ? xs1 : xs0;
    const size_t basel = (size_t)bk*LL;
    const int l0 = c*CS;

    float h = 0.f, p = 1.f;
    #pragma unroll 4
    for (int i = 0; i < CS; ++i) {
        int l = l0 + i;
        float dt = delta[(basel + l)*DI + d];
        int lp = rev ? (LL-1-l) : l;
        float u  = src[((size_t)b*LL + lp)*DI + d];
        float Bn = Bsb[(basel + l)*NS + n];
        float dA = __expf(dt * A);
        h = fmaf(dA, h, dt * Bn * u);
        p *= dA;
    }
    size_t idx = ((size_t)(bk*DI + d)*NS + n)*NC + c;
    P[idx] = p;
    Hend[idx] = h;
}

// ------------- kernel 4b: combine chunk states sequentially -------------
__global__ __launch_bounds__(256) void k_scanmid(const float* __restrict__ P,
                                                 const float* __restrict__ Hend,
                                                 float* __restrict__ Hin) {
    int idx = blockIdx.x*256 + threadIdx.x;     // 0 .. B*K*DI*NS-1
    const float* Pp = P    + (size_t)idx*NC;
    const float* He = Hend + (size_t)idx*NC;
    float*       Hi = Hin  + (size_t)idx*NC;
    float h = 0.f;
    #pragma unroll
    for (int c = 0; c < NC; ++c) {
        Hi[c] = h;
        h = fmaf(Pp[c], h, He[c]);
    }
}

// ------------- kernel 4c: chunked scan pass 2 — rescan with true h_in, emit y -------------
__global__ __launch_bounds__(64) void k_scan2(const float* __restrict__ delta,
                                              const float* __restrict__ xs0,
                                              const float* __restrict__ xs1,
                                              const float* __restrict__ Bsb,
                                              const float* __restrict__ Csb,
                                              const float* __restrict__ A_logs,
                                              const float* __restrict__ Ds,
                                              const float* __restrict__ Hin,
                                              float* __restrict__ oy) {
    int bk = blockIdx.z;
    int k = bk & 3, b = bk >> 2;
    int c = blockIdx.y;
    int t = threadIdx.x;
    int d = blockIdx.x*4 + (t >> 4);
    int n = t & 15;
    int kd = k*DI + d;
    const float A  = -expf(A_logs[kd*NS + n]);
    const float Dv = Ds[kd];
    const bool rev = (k >= 2);
    const float* src = (k & 1) ? xs1 : xs0;
    const size_t basel = (size_t)bk*LL;
    const int l0 = c*CS;

    float h = Hin[((size_t)(bk*DI + d)*NS + n)*NC + c];
    #pragma unroll 4
    for (int i = 0; i < CS; ++i) {
        int l = l0 + i;
        float dt = delta[(basel + l)*DI + d];
        int lp = rev ? (LL-1-l) : l;
        float u  = src[((size_t)b*LL + lp)*DI + d];
        float Bn = Bsb[(basel + l)*NS + n];
        float Cn = Csb[(basel + l)*NS + n];
        float dA = __expf(dt * A);
        h = fmaf(dA, h, dt * Bn * u);
        float py = h * Cn;
        py += __shfl_xor(py, 1);
        py += __shfl_xor(py, 2);
        py += __shfl_xor(py, 4);
        py += __shfl_xor(py, 8);
        if (n == 0) oy[(basel + l)*DI + d] = fmaf(u, Dv, py);
    }
}

// ------------- kernel 5: gather 4 streams + LayerNorm + silu gate + out_proj -------------
__global__ __launch_bounds__(DI) void k_out(const float* __restrict__ oy,
                                            const float* __restrict__ zsilu,
                                            const float* __restrict__ onw,
                                            const float* __restrict__ onb,
                                            const float* __restrict__ opw,   // (96,192)
                                            float* __restrict__ out) {
    int bl = blockIdx.x;
    int b = bl / LL, l = bl % LL;
    int h = l / WW, w = l % WW;
    int i  = (w & 1) ? (HH-1-h) : h;
    int l0 = i*WW + w;
    int l1 = ((i & 1) ? (WW-1-w) : w)*HH + i;
    int t = threadIdx.x;
    size_t base = (size_t)b*KK*LL*DI;
    float yd = oy[base + (size_t)(0*LL + l0)*DI + t]
             + oy[base + (size_t)(1*LL + l1)*DI + t]
             + oy[base + (size_t)(2*LL + (LL-1-l0))*DI + t]
             + oy[base + (size_t)(3*LL + (LL-1-l1))*DI + t];

    __shared__ float red[8];
    __shared__ float yv[DI];
    float s1 = yd, s2 = yd*yd;
    #pragma unroll
    for (int m = 1; m < 64; m <<= 1) { s1 += __shfl_xor(s1, m); s2 += __shfl_xor(s2, m); }
    int wave = t >> 6;
    if ((t & 63) == 0) { red[wave] = s1; red[4 + wave] = s2; }
    __syncthreads();
    float tot1 = red[0] + red[1] + red[2];
    float tot2 = red[4] + red[5] + red[6];
    float mu  = tot1 / DI;
    float var = tot2 / DI - mu*mu;
    float ry  = rsqrtf(var + 1e-5f);
    float yn  = (yd - mu) * ry * onw[t] + onb[t];
    yv[t] = yn * zsilu[(size_t)bl*DI + t];
    __syncthreads();
    if (t < DM) {
        float acc = 0.f;
        const float* wr = opw + t*DI;
        #pragma unroll 8
        for (int i2 = 0; i2 < DI; ++i2) acc = fmaf(wr[i2], yv[i2], acc);
        out[(size_t)bl*DM + t] = acc;
    }
}

extern "C" void kernel_launch(void* const* d_in, const int* in_sizes, int n_in,
                              void* d_out, int out_size, void* d_ws, size_t ws_size,
                              hipStream_t stream) {
    const float* x      = (const float*)d_in[0];
    const float* ipw    = (const float*)d_in[1];
    const float* convw  = (const float*)d_in[2];
    const float* convb  = (const float*)d_in[3];
    const float* xpw    = (const float*)d_in[4];
    const float* dtw    = (const float*)d_in[5];
    const float* dtb    = (const float*)d_in[6];
    const float* A_logs = (const float*)d_in[7];
    const float* Ds     = (const float*)d_in[8];
    const float* onw    = (const float*)d_in[9];
    const float* onb    = (const float*)d_in[10];
    const float* opw    = (const float*)d_in[11];
    float* out = (float*)d_out;

    float* ws = (float*)d_ws;
    const size_t SZ_BLD  = (size_t)BB*LL*DI;      // 1,204,224
    const size_t SZ_BKLD = (size_t)BB*KK*LL*DI;   // 4,816,896
    const size_t SZ_BKLN = (size_t)BB*KK*LL*NS;   //   401,408
    const size_t SZ_P    = (size_t)BB*KK*DI*NS*NC; // 1,204,224 (== SZ_BLD)
    float* xcpre = ws;                // dead after k_conv -> reused as P
    float* zsilu = xcpre + SZ_BLD;
    float* xs0   = zsilu + SZ_BLD;
    float* xs1   = xs0   + SZ_BLD;
    float* delta = xs1   + SZ_BLD;
    float* Bsb   = delta + SZ_BKLD;
    float* Csb   = Bsb   + SZ_BKLN;
    float* oy    = Csb   + SZ_BKLN;
    float* Hin   = oy    + SZ_BKLD;   // only new allocation (+4.8 MB)
    float* P     = xcpre;             // alias: xcpre dead after k_conv
    float* Hend  = oy;                // alias: oy head unwritten until k_scan2

    k_inproj<<<BB*LL, 384, 0, stream>>>(x, ipw, xcpre, zsilu);
    k_conv<<<BB*LL, DI, 0, stream>>>(xcpre, convw, convb, xs0, xs1);
    dim3 g3(LL/TL, KK, BB);
    k_proj<<<g3, 256, 0, stream>>>(xs0, xs1, xpw, dtw, dtb, delta, Bsb, Csb);
    dim3 g4(DI/4, NC, BB*KK);
    k_scan1<<<g4, 64, 0, stream>>>(delta, xs0, xs1, Bsb, A_logs, P, Hend);
    k_scanmid<<<(BB*KK*DI*NS)/256, 256, 0, stream>>>(P, Hend, Hin);
    k_scan2<<<g4, 64, 0, stream>>>(delta, xs0, xs1, Bsb, Csb, A_logs, Ds, Hin, oy);
    k_out<<<BB*LL, DI, 0, stream>>>(oy, zsilu, onw, onb, opw, out);
}

// Round 3
// 356.733 us; speedup vs baseline: 4.6417x; 1.3199x over previous
//
#include <hip/hip_runtime.h>
#include <hip/hip_bf16.h>

#define BB 2
#define HH 56
#define WW 56
#define LL (HH*WW)          // 3136
#define DM 96
#define DI 192
#define NS 16               // d_state
#define DTR 6
#define KK 4
#define CDBL (DTR + 2*NS)   // 38
#define CS 64               // scan chunk size
#define NC 49               // number of chunks (CS*NC == LL)

// ---------------- kernel 1: in_proj as tiled GEMM ----------------
// C(6272 x 384) = X(6272 x 96) @ W^T(96 x 384); BM=32 positions per block.
#define IP_BM 32
__global__ __launch_bounds__(256) void k_inproj(const float* __restrict__ x,
                                                const float* __restrict__ w,
                                                float* __restrict__ xcpre,
                                                float* __restrict__ zsilu) {
    __shared__ float xl[IP_BM*100];   // stride 100 (4-aligned, bank-spread)
    __shared__ float wl[64*100];
    int t = threadIdx.x;
    int bl0 = blockIdx.x * IP_BM;
    for (int idx = t; idx < IP_BM*96; idx += 256) {
        int r = idx/96, c = idx%96;
        xl[r*100+c] = x[(bl0+r)*DM + c];
    }
    int pg = t >> 4, eg = t & 15;     // pg 0..15 -> 2 positions, eg 0..15 -> 4 channels
    for (int nc = 0; nc < 6; ++nc) {
        __syncthreads();
        for (int idx = t; idx < 64*96; idx += 256) {
            int r = idx/96, c = idx%96;
            wl[r*100+c] = w[(nc*64+r)*DM + c];
        }
        __syncthreads();
        float acc[2][4] = {};
        #pragma unroll 4
        for (int k = 0; k < 96; ++k) {
            float a0 = xl[(pg*2+0)*100+k];
            float a1 = xl[(pg*2+1)*100+k];
            float b0 = wl[(eg*4+0)*100+k];
            float b1 = wl[(eg*4+1)*100+k];
            float b2 = wl[(eg*4+2)*100+k];
            float b3 = wl[(eg*4+3)*100+k];
            acc[0][0] = fmaf(a0,b0,acc[0][0]); acc[0][1] = fmaf(a0,b1,acc[0][1]);
            acc[0][2] = fmaf(a0,b2,acc[0][2]); acc[0][3] = fmaf(a0,b3,acc[0][3]);
            acc[1][0] = fmaf(a1,b0,acc[1][0]); acc[1][1] = fmaf(a1,b1,acc[1][1]);
            acc[1][2] = fmaf(a1,b2,acc[1][2]); acc[1][3] = fmaf(a1,b3,acc[1][3]);
        }
        #pragma unroll
        for (int j = 0; j < 2; ++j) {
            int bl = bl0 + pg*2 + j;
            #pragma unroll
            for (int jj = 0; jj < 4; ++jj) {
                int e = nc*64 + eg*4 + jj;
                float v = acc[j][jj];
                if (e < DI) xcpre[(size_t)bl*DI + e] = v;
                else        zsilu[(size_t)bl*DI + (e-DI)] = v / (1.f + expf(-v));
            }
        }
    }
}

// ------------- kernel 2: depthwise 3x3 conv + bias + silu + scan scatter -------------
__global__ __launch_bounds__(DI) void k_conv(const float* __restrict__ xcpre,
                                             const float* __restrict__ cw,
                                             const float* __restrict__ cb,
                                             float* __restrict__ xs0,
                                             float* __restrict__ xs1) {
    int bl = blockIdx.x;
    int b = bl / LL, l = bl % LL;
    int h = l / WW, w = l % WW;
    int c = threadIdx.x;
    float acc = cb[c];
    #pragma unroll
    for (int dh = -1; dh <= 1; ++dh) {
        int hh = h + dh;
        if (hh < 0 || hh >= HH) continue;
        #pragma unroll
        for (int dw = -1; dw <= 1; ++dw) {
            int ww2 = w + dw;
            if (ww2 < 0 || ww2 >= WW) continue;
            acc = fmaf(xcpre[(b*LL + hh*WW + ww2)*DI + c],
                       cw[c*9 + (dh+1)*3 + (dw+1)], acc);
        }
    }
    float v = acc / (1.f + expf(-acc));   // silu
    int i  = (w & 1) ? (HH-1-h) : h;
    int l0 = i*WW + w;
    int l1 = ((i & 1) ? (WW-1-w) : w)*HH + i;
    xs0[(b*LL + l0)*DI + c] = v;
    xs1[(b*LL + l1)*DI + c] = v;
}

// ------------- kernel 3: x_proj (38x192) + dt_proj (192x6) + softplus -------------
#define TL 32
__global__ __launch_bounds__(256) void k_proj(const float* __restrict__ xs0,
                                              const float* __restrict__ xs1,
                                              const float* __restrict__ xpw,   // (K,38,192)
                                              const float* __restrict__ dtw,   // (K,192,6)
                                              const float* __restrict__ dtb,   // (K,192)
                                              float* __restrict__ delta,       // (B,K,L,192)
                                              float* __restrict__ Bsb,         // (B,K,L,16)
                                              float* __restrict__ Csb) {       // (B,K,L,16)
    int tile = blockIdx.x, k = blockIdx.y, b = blockIdx.z;
    int t = threadIdx.x;
    __shared__ float Wl[CDBL*DI];      // 38*192
    __shared__ float dtWl[DI*DTR];     // 192*6
    __shared__ float dtbl[DI];
    __shared__ float Xl[TL*193];       // padded stride 193
    __shared__ float dblL[DTR*33];     // dt rows, padded

    for (int idx = t; idx < CDBL*DI; idx += 256) Wl[idx] = xpw[k*CDBL*DI + idx];
    for (int idx = t; idx < DI*DTR;  idx += 256) dtWl[idx] = dtw[k*DI*DTR + idx];
    if (t < DI) dtbl[t] = dtb[k*DI + t];
    const float* src = (k & 1) ? xs1 : xs0;
    for (int idx = t; idx < TL*DI; idx += 256) {
        int ll = idx / DI, i = idx % DI;
        int lg = tile*TL + ll;
        int lp = (k >= 2) ? (LL-1-lg) : lg;
        Xl[ll*193 + i] = src[(b*LL + lp)*DI + i];
    }
    __syncthreads();

    for (int idx = t; idx < CDBL*TL; idx += 256) {
        int c = idx >> 5, ll = idx & 31;
        float acc = 0.f;
        #pragma unroll 8
        for (int i = 0; i < DI; ++i) acc = fmaf(Wl[c*DI + i], Xl[ll*193 + i], acc);
        int lg = tile*TL + ll;
        if (c < DTR) {
            dblL[c*33 + ll] = acc;
        } else if (c < DTR + NS) {
            Bsb[((b*KK + k)*LL + lg)*NS + (c - DTR)] = acc;
        } else {
            Csb[((b*KK + k)*LL + lg)*NS + (c - DTR - NS)] = acc;
        }
    }
    __syncthreads();

    for (int idx = t; idx < DI*TL; idx += 256) {
        int d = idx % DI, ll = idx / DI;
        float acc = dtbl[d];
        #pragma unroll
        for (int r = 0; r < DTR; ++r) acc = fmaf(dtWl[d*DTR + r], dblL[r*33 + ll], acc);
        float sp = fmaxf(acc, 0.f) + log1pf(expf(-fabsf(acc)));
        delta[((b*KK + k)*LL + tile*TL + ll)*DI + d] = sp;
    }
}

// ------------- kernel 4a: chunked scan pass 1 -------------
__global__ __launch_bounds__(64) void k_scan1(const float* __restrict__ delta,
                                              const float* __restrict__ xs0,
                                              const float* __restrict__ xs1,
                                              const float* __restrict__ Bsb,
                                              const float* __restrict__ A_logs,
                                              float* __restrict__ P,     // (B*K*DI*NS, NC)
                                              float* __restrict__ Hend) {
    int bk = blockIdx.z;
    int k = bk & 3, b = bk >> 2;
    int c = blockIdx.y;
    int t = threadIdx.x;
    int d = blockIdx.x*4 + (t >> 4);
    int n = t & 15;
    int kd = k*DI + d;
    const float A = -expf(A_logs[kd*NS + n]);
    const bool rev = (k >= 2);
    const float* src = (k & 1) ? xs1 : xs0;
    const size_t basel = (size_t)bk*LL;
    const int l0 = c*CS;

    float h = 0.f, p = 1.f;
    #pragma unroll 4
    for (int i = 0; i < CS; ++i) {
        int l = l0 + i;
        float dt = delta[(basel + l)*DI + d];
        int lp = rev ? (LL-1-l) : l;
        float u  = src[((size_t)b*LL + lp)*DI + d];
        float Bn = Bsb[(basel + l)*NS + n];
        float dA = __expf(dt * A);
        h = fmaf(dA, h, dt * Bn * u);
        p *= dA;
    }
    size_t idx = ((size_t)(bk*DI + d)*NS + n)*NC + c;
    P[idx] = p;
    Hend[idx] = h;
}

// ------------- kernel 4b: combine chunk states sequentially -------------
__global__ __launch_bounds__(256) void k_scanmid(const float* __restrict__ P,
                                                 const float* __restrict__ Hend,
                                                 float* __restrict__ Hin) {
    int idx = blockIdx.x*256 + threadIdx.x;
    const float* Pp = P    + (size_t)idx*NC;
    const float* He = Hend + (size_t)idx*NC;
    float*       Hi = Hin  + (size_t)idx*NC;
    float h = 0.f;
    #pragma unroll
    for (int c = 0; c < NC; ++c) {
        Hi[c] = h;
        h = fmaf(Pp[c], h, He[c]);
    }
}

// ------------- kernel 4c: chunked scan pass 2 -------------
__global__ __launch_bounds__(64) void k_scan2(const float* __restrict__ delta,
                                              const float* __restrict__ xs0,
                                              const float* __restrict__ xs1,
                                              const float* __restrict__ Bsb,
                                              const float* __restrict__ Csb,
                                              const float* __restrict__ A_logs,
                                              const float* __restrict__ Ds,
                                              const float* __restrict__ Hin,
                                              float* __restrict__ oy) {
    int bk = blockIdx.z;
    int k = bk & 3, b = bk >> 2;
    int c = blockIdx.y;
    int t = threadIdx.x;
    int d = blockIdx.x*4 + (t >> 4);
    int n = t & 15;
    int kd = k*DI + d;
    const float A  = -expf(A_logs[kd*NS + n]);
    const float Dv = Ds[kd];
    const bool rev = (k >= 2);
    const float* src = (k & 1) ? xs1 : xs0;
    const size_t basel = (size_t)bk*LL;
    const int l0 = c*CS;

    float h = Hin[((size_t)(bk*DI + d)*NS + n)*NC + c];
    #pragma unroll 4
    for (int i = 0; i < CS; ++i) {
        int l = l0 + i;
        float dt = delta[(basel + l)*DI + d];
        int lp = rev ? (LL-1-l) : l;
        float u  = src[((size_t)b*LL + lp)*DI + d];
        float Bn = Bsb[(basel + l)*NS + n];
        float Cn = Csb[(basel + l)*NS + n];
        float dA = __expf(dt * A);
        h = fmaf(dA, h, dt * Bn * u);
        float py = h * Cn;
        py += __shfl_xor(py, 1);
        py += __shfl_xor(py, 2);
        py += __shfl_xor(py, 4);
        py += __shfl_xor(py, 8);
        if (n == 0) oy[(basel + l)*DI + d] = fmaf(u, Dv, py);
    }
}

// ------------- kernel 5: gather + LayerNorm + gate, then tiled GEMM out_proj -------------
// 32 positions per block; 256 threads (4 waves x 8 positions each).
#define OP_BM 32
__global__ __launch_bounds__(256) void k_out(const float* __restrict__ oy,
                                             const float* __restrict__ zsilu,
                                             const float* __restrict__ onw,
                                             const float* __restrict__ onb,
                                             const float* __restrict__ opw,   // (96,192)
                                             float* __restrict__ out) {
    __shared__ float yv[OP_BM*196];   // stride 196 (4-aligned)
    __shared__ float wl[96*68];       // opw k-chunk, stride 68
    int t = threadIdx.x;
    int bl0 = blockIdx.x * OP_BM;
    int lane = t & 63, wv = t >> 6;

    for (int pp = 0; pp < 8; ++pp) {
        int p = wv*8 + pp;
        int bl = bl0 + p;
        int b = bl / LL, l = bl % LL;
        int h = l / WW, w2 = l % WW;
        int i = (w2 & 1) ? (HH-1-h) : h;
        int l0 = i*WW + w2;
        int l1 = ((i & 1) ? (WW-1-w2) : w2)*HH + i;
        size_t base = (size_t)b*KK*LL*DI;
        float yd[3]; float s1 = 0.f, s2 = 0.f;
        #pragma unroll
        for (int j = 0; j < 3; ++j) {
            int c = lane + j*64;
            float v = oy[base + (size_t)(0*LL + l0)*DI + c]
                    + oy[base + (size_t)(1*LL + l1)*DI + c]
                    + oy[base + (size_t)(2*LL + (LL-1-l0))*DI + c]
                    + oy[base + (size_t)(3*LL + (LL-1-l1))*DI + c];
            yd[j] = v; s1 += v; s2 += v*v;
        }
        #pragma unroll
        for (int m = 1; m < 64; m <<= 1) { s1 += __shfl_xor(s1, m); s2 += __shfl_xor(s2, m); }
        float mu  = s1 / DI;
        float var = s2 / DI - mu*mu;
        float ry  = rsqrtf(var + 1e-5f);
        #pragma unroll
        for (int j = 0; j < 3; ++j) {
            int c = lane + j*64;
            float yn = (yd[j] - mu) * ry * onw[c] + onb[c];
            yv[p*196 + c] = yn * zsilu[(size_t)bl*DI + c];
        }
    }

    int pg = t >> 5, eg = t & 31;     // pg 0..7 -> 4 positions, eg 0..31 -> 3 channels
    float acc[4][3] = {};
    for (int kc = 0; kc < 3; ++kc) {
        __syncthreads();
        for (int idx = t; idx < 96*64; idx += 256) {
            int r = idx >> 6, c = idx & 63;
            wl[r*68 + c] = opw[r*DI + kc*64 + c];
        }
        __syncthreads();
        #pragma unroll 4
        for (int kk = 0; kk < 64; ++kk) {
            float a[4], bq[3];
            #pragma unroll
            for (int j = 0; j < 4; ++j)  a[j]  = yv[(pg*4+j)*196 + kc*64 + kk];
            #pragma unroll
            for (int jj = 0; jj < 3; ++jj) bq[jj] = wl[(eg*3+jj)*68 + kk];
            #pragma unroll
            for (int j = 0; j < 4; ++j)
                #pragma unroll
                for (int jj = 0; jj < 3; ++jj)
                    acc[j][jj] = fmaf(a[j], bq[jj], acc[j][jj]);
        }
    }
    #pragma unroll
    for (int j = 0; j < 4; ++j) {
        int bl = bl0 + pg*4 + j;
        #pragma unroll
        for (int jj = 0; jj < 3; ++jj)
            out[(size_t)bl*DM + eg*3 + jj] = acc[j][jj];
    }
}

extern "C" void kernel_launch(void* const* d_in, const int* in_sizes, int n_in,
                              void* d_out, int out_size, void* d_ws, size_t ws_size,
                              hipStream_t stream) {
    const float* x      = (const float*)d_in[0];
    const float* ipw    = (const float*)d_in[1];
    const float* convw  = (const float*)d_in[2];
    const float* convb  = (const float*)d_in[3];
    const float* xpw    = (const float*)d_in[4];
    const float* dtw    = (const float*)d_in[5];
    const float* dtb    = (const float*)d_in[6];
    const float* A_logs = (const float*)d_in[7];
    const float* Ds     = (const float*)d_in[8];
    const float* onw    = (const float*)d_in[9];
    const float* onb    = (const float*)d_in[10];
    const float* opw    = (const float*)d_in[11];
    float* out = (float*)d_out;

    float* ws = (float*)d_ws;
    const size_t SZ_BLD  = (size_t)BB*LL*DI;
    const size_t SZ_BKLD = (size_t)BB*KK*LL*DI;
    const size_t SZ_BKLN = (size_t)BB*KK*LL*NS;
    float* xcpre = ws;                // dead after k_conv -> reused as P
    float* zsilu = xcpre + SZ_BLD;
    float* xs0   = zsilu + SZ_BLD;
    float* xs1   = xs0   + SZ_BLD;
    float* delta = xs1   + SZ_BLD;
    float* Bsb   = delta + SZ_BKLD;
    float* Csb   = Bsb   + SZ_BKLN;
    float* oy    = Csb   + SZ_BKLN;
    float* Hin   = oy    + SZ_BKLD;
    float* P     = xcpre;
    float* Hend  = oy;

    k_inproj<<<(BB*LL)/IP_BM, 256, 0, stream>>>(x, ipw, xcpre, zsilu);
    k_conv<<<BB*LL, DI, 0, stream>>>(xcpre, convw, convb, xs0, xs1);
    dim3 g3(LL/TL, KK, BB);
    k_proj<<<g3, 256, 0, stream>>>(xs0, xs1, xpw, dtw, dtb, delta, Bsb, Csb);
    dim3 g4(DI/4, NC, BB*KK);
    k_scan1<<<g4, 64, 0, stream>>>(delta, xs0, xs1, Bsb, A_logs, P, Hend);
    k_scanmid<<<(BB*KK*DI*NS)/256, 256, 0, stream>>>(P, Hend, Hin);
    k_scan2<<<g4, 64, 0, stream>>>(delta, xs0, xs1, Bsb, Csb, A_logs, Ds, Hin, oy);
    k_out<<<(BB*LL)/OP_BM, 256, 0, stream>>>(oy, zsilu, onw, onb, opw, out);
}

// Round 5
// 273.664 us; speedup vs baseline: 6.0506x; 1.3035x over previous
//
#include <hip/hip_runtime.h>
#include <hip/hip_bf16.h>

#define BB 2
#define HH 56
#define WW 56
#define LL (HH*WW)          // 3136
#define DM 96
#define DI 192
#define NS 16               // d_state
#define DTR 6
#define KK 4
#define CDBL (DTR + 2*NS)   // 38
#define CS 32               // scan chunk size
#define NC 98               // number of chunks (CS*NC == LL)
#define ROWS (BB*KK*DI)     // 1536 state rows (x NS cols) per chunk

// ---------------- kernel 1: in_proj as tiled GEMM ----------------
#define IP_BM 32
__global__ __launch_bounds__(256) void k_inproj(const float* __restrict__ x,
                                                const float* __restrict__ w,
                                                float* __restrict__ xcpre,
                                                float* __restrict__ zsilu) {
    __shared__ float xl[IP_BM*100];
    __shared__ float wl[64*100];
    int t = threadIdx.x;
    int bl0 = blockIdx.x * IP_BM;
    for (int idx = t; idx < IP_BM*96; idx += 256) {
        int r = idx/96, c = idx%96;
        xl[r*100+c] = x[(bl0+r)*DM + c];
    }
    int pg = t >> 4, eg = t & 15;
    for (int nc = 0; nc < 6; ++nc) {
        __syncthreads();
        for (int idx = t; idx < 64*96; idx += 256) {
            int r = idx/96, c = idx%96;
            wl[r*100+c] = w[(nc*64+r)*DM + c];
        }
        __syncthreads();
        float acc[2][4] = {};
        #pragma unroll 4
        for (int k = 0; k < 96; ++k) {
            float a0 = xl[(pg*2+0)*100+k];
            float a1 = xl[(pg*2+1)*100+k];
            float b0 = wl[(eg*4+0)*100+k];
            float b1 = wl[(eg*4+1)*100+k];
            float b2 = wl[(eg*4+2)*100+k];
            float b3 = wl[(eg*4+3)*100+k];
            acc[0][0] = fmaf(a0,b0,acc[0][0]); acc[0][1] = fmaf(a0,b1,acc[0][1]);
            acc[0][2] = fmaf(a0,b2,acc[0][2]); acc[0][3] = fmaf(a0,b3,acc[0][3]);
            acc[1][0] = fmaf(a1,b0,acc[1][0]); acc[1][1] = fmaf(a1,b1,acc[1][1]);
            acc[1][2] = fmaf(a1,b2,acc[1][2]); acc[1][3] = fmaf(a1,b3,acc[1][3]);
        }
        #pragma unroll
        for (int j = 0; j < 2; ++j) {
            int bl = bl0 + pg*2 + j;
            #pragma unroll
            for (int jj = 0; jj < 4; ++jj) {
                int e = nc*64 + eg*4 + jj;
                float v = acc[j][jj];
                if (e < DI) xcpre[(size_t)bl*DI + e] = v;
                else        zsilu[(size_t)bl*DI + (e-DI)] = v / (1.f + expf(-v));
            }
        }
    }
}

// ------------- kernel 2: depthwise 3x3 conv + bias + silu + scan scatter -------------
__global__ __launch_bounds__(DI) void k_conv(const float* __restrict__ xcpre,
                                             const float* __restrict__ cw,
                                             const float* __restrict__ cb,
                                             float* __restrict__ xs0,
                                             float* __restrict__ xs1) {
    int bl = blockIdx.x;
    int b = bl / LL, l = bl % LL;
    int h = l / WW, w = l % WW;
    int c = threadIdx.x;
    float acc = cb[c];
    #pragma unroll
    for (int dh = -1; dh <= 1; ++dh) {
        int hh = h + dh;
        if (hh < 0 || hh >= HH) continue;
        #pragma unroll
        for (int dw = -1; dw <= 1; ++dw) {
            int ww2 = w + dw;
            if (ww2 < 0 || ww2 >= WW) continue;
            acc = fmaf(xcpre[(b*LL + hh*WW + ww2)*DI + c],
                       cw[c*9 + (dh+1)*3 + (dw+1)], acc);
        }
    }
    float v = acc / (1.f + expf(-acc));   // silu
    int i  = (w & 1) ? (HH-1-h) : h;
    int l0 = i*WW + w;
    int l1 = ((i & 1) ? (WW-1-w) : w)*HH + i;
    xs0[(b*LL + l0)*DI + c] = v;
    xs1[(b*LL + l1)*DI + c] = v;
}

// ------------- kernel 3: x_proj (38x192) + dt_proj (192x6) + softplus -------------
#define TL 32
__global__ __launch_bounds__(256) void k_proj(const float* __restrict__ xs0,
                                              const float* __restrict__ xs1,
                                              const float* __restrict__ xpw,
                                              const float* __restrict__ dtw,
                                              const float* __restrict__ dtb,
                                              float* __restrict__ delta,
                                              float* __restrict__ Bsb,
                                              float* __restrict__ Csb) {
    int tile = blockIdx.x, k = blockIdx.y, b = blockIdx.z;
    int t = threadIdx.x;
    __shared__ float Wl[CDBL*DI];
    __shared__ float dtWl[DI*DTR];
    __shared__ float dtbl[DI];
    __shared__ float Xl[TL*193];
    __shared__ float dblL[DTR*33];

    for (int idx = t; idx < CDBL*DI; idx += 256) Wl[idx] = xpw[k*CDBL*DI + idx];
    for (int idx = t; idx < DI*DTR;  idx += 256) dtWl[idx] = dtw[k*DI*DTR + idx];
    if (t < DI) dtbl[t] = dtb[k*DI + t];
    const float* src = (k & 1) ? xs1 : xs0;
    for (int idx = t; idx < TL*DI; idx += 256) {
        int ll = idx / DI, i = idx % DI;
        int lg = tile*TL + ll;
        int lp = (k >= 2) ? (LL-1-lg) : lg;
        Xl[ll*193 + i] = src[(b*LL + lp)*DI + i];
    }
    __syncthreads();

    for (int idx = t; idx < CDBL*TL; idx += 256) {
        int c = idx >> 5, ll = idx & 31;
        float acc = 0.f;
        #pragma unroll 8
        for (int i = 0; i < DI; ++i) acc = fmaf(Wl[c*DI + i], Xl[ll*193 + i], acc);
        int lg = tile*TL + ll;
        if (c < DTR) {
            dblL[c*33 + ll] = acc;
        } else if (c < DTR + NS) {
            Bsb[((b*KK + k)*LL + lg)*NS + (c - DTR)] = acc;
        } else {
            Csb[((b*KK + k)*LL + lg)*NS + (c - DTR - NS)] = acc;
        }
    }
    __syncthreads();

    for (int idx = t; idx < DI*TL; idx += 256) {
        int d = idx % DI, ll = idx / DI;
        float acc = dtbl[d];
        #pragma unroll
        for (int r = 0; r < DTR; ++r) acc = fmaf(dtWl[d*DTR + r], dblL[r*33 + ll], acc);
        float sp = fmaxf(acc, 0.f) + log1pf(expf(-fabsf(acc)));
        delta[((b*KK + k)*LL + tile*TL + ll)*DI + d] = sp;
    }
}

// ------------- kernel 4a: chunked scan pass 1 — thread = d, 16 n-states in regs -------------
// block = 192 threads (all of DI); grid = (NC, B*K)
__global__ __launch_bounds__(192) void k_scan1(const float* __restrict__ delta,
                                               const float* __restrict__ xs0,
                                               const float* __restrict__ xs1,
                                               const float* __restrict__ Bsb,
                                               const float* __restrict__ A_logs,
                                               float* __restrict__ P,     // [c][bk*DI+d][n]
                                               float* __restrict__ Hend) {
    int c = blockIdx.x, bk = blockIdx.y;
    int k = bk & 3, b = bk >> 2;
    int d = threadIdx.x;
    int kd = k*DI + d;
    __shared__ float Bl[CS*NS];
    const float* bsrc = Bsb + ((size_t)bk*LL + c*CS)*NS;
    for (int i = threadIdx.x; i < CS*NS/4; i += 192)
        ((float4*)Bl)[i] = ((const float4*)bsrc)[i];

    float A[NS], h[NS], p[NS];
    #pragma unroll
    for (int q = 0; q < 4; ++q) {
        float4 av = *(const float4*)&A_logs[kd*NS + 4*q];
        A[4*q+0] = -expf(av.x); A[4*q+1] = -expf(av.y);
        A[4*q+2] = -expf(av.z); A[4*q+3] = -expf(av.w);
    }
    #pragma unroll
    for (int n = 0; n < NS; ++n) { h[n] = 0.f; p[n] = 1.f; }
    __syncthreads();

    const bool rev = (k >= 2);
    const float* dp = delta + ((size_t)bk*LL + c*CS)*DI + d;
    const float* up = ((k & 1) ? xs1 : xs0) + (size_t)b*LL*DI + d;
    const int l0 = c*CS;

    #pragma unroll 2
    for (int i = 0; i < CS; ++i) {
        float dt = dp[(size_t)i*DI];
        int lp = rev ? (LL-1-(l0+i)) : (l0+i);
        float u = up[(size_t)lp*DI];
        float dtu = dt * u;
        float Bv[NS];
        #pragma unroll
        for (int q = 0; q < 4; ++q)
            *(float4*)&Bv[4*q] = *(const float4*)&Bl[i*NS + 4*q];
        #pragma unroll
        for (int n = 0; n < NS; ++n) {
            float dA = __expf(dt * A[n]);
            h[n] = fmaf(dA, h[n], dtu * Bv[n]);
            p[n] *= dA;
        }
    }
    size_t obase = ((size_t)c*ROWS + bk*DI + d)*NS;
    #pragma unroll
    for (int q = 0; q < 4; ++q) {
        *(float4*)&P[obase + 4*q]    = make_float4(p[4*q], p[4*q+1], p[4*q+2], p[4*q+3]);
        *(float4*)&Hend[obase + 4*q] = make_float4(h[4*q], h[4*q+1], h[4*q+2], h[4*q+3]);
    }
}

// ------------- kernel 4b: combine chunk states sequentially -------------
__global__ __launch_bounds__(256) void k_scanmid(const float* __restrict__ P,
                                                 const float* __restrict__ Hend,
                                                 float* __restrict__ Hin) {
    int tid = blockIdx.x*256 + threadIdx.x;     // 0 .. ROWS*NS-1
    float h = 0.f;
    for (int c = 0; c < NC; ++c) {
        size_t idx = (size_t)c*(ROWS*NS) + tid;
        Hin[idx] = h;
        h = fmaf(P[idx], h, Hend[idx]);
    }
}

// ------------- kernel 4c: chunked scan pass 2 — rescan with true h_in, emit y -------------
__global__ __launch_bounds__(192) void k_scan2(const float* __restrict__ delta,
                                               const float* __restrict__ xs0,
                                               const float* __restrict__ xs1,
                                               const float* __restrict__ Bsb,
                                               const float* __restrict__ Csb,
                                               const float* __restrict__ A_logs,
                                               const float* __restrict__ Ds,
                                               const float* __restrict__ Hin,
                                               float* __restrict__ oy) {
    int c = blockIdx.x, bk = blockIdx.y;
    int k = bk & 3, b = bk >> 2;
    int d = threadIdx.x;
    int kd = k*DI + d;
    __shared__ float Bl[CS*NS];
    __shared__ float Cl[CS*NS];
    const float* bsrc = Bsb + ((size_t)bk*LL + c*CS)*NS;
    const float* csrc = Csb + ((size_t)bk*LL + c*CS)*NS;
    for (int i = threadIdx.x; i < CS*NS/4; i += 192) {
        ((float4*)Bl)[i] = ((const float4*)bsrc)[i];
        ((float4*)Cl)[i] = ((const float4*)csrc)[i];
    }

    float A[NS], h[NS];
    #pragma unroll
    for (int q = 0; q < 4; ++q) {
        float4 av = *(const float4*)&A_logs[kd*NS + 4*q];
        A[4*q+0] = -expf(av.x); A[4*q+1] = -expf(av.y);
        A[4*q+2] = -expf(av.z); A[4*q+3] = -expf(av.w);
    }
    size_t ibase = ((size_t)c*ROWS + bk*DI + d)*NS;
    #pragma unroll
    for (int q = 0; q < 4; ++q) {
        float4 hv = *(const float4*)&Hin[ibase + 4*q];
        h[4*q+0] = hv.x; h[4*q+1] = hv.y; h[4*q+2] = hv.z; h[4*q+3] = hv.w;
    }
    const float Dv = Ds[kd];
    __syncthreads();

    const bool rev = (k >= 2);
    const float* dp = delta + ((size_t)bk*LL + c*CS)*DI + d;
    const float* up = ((k & 1) ? xs1 : xs0) + (size_t)b*LL*DI + d;
    float* yp = oy + ((size_t)bk*LL + c*CS)*DI + d;
    const int l0 = c*CS;

    #pragma unroll 2
    for (int i = 0; i < CS; ++i) {
        float dt = dp[(size_t)i*DI];
        int lp = rev ? (LL-1-(l0+i)) : (l0+i);
        float u = up[(size_t)lp*DI];
        float dtu = dt * u;
        float Bv[NS], Cv[NS];
        #pragma unroll
        for (int q = 0; q < 4; ++q) {
            *(float4*)&Bv[4*q] = *(const float4*)&Bl[i*NS + 4*q];
            *(float4*)&Cv[4*q] = *(const float4*)&Cl[i*NS + 4*q];
        }
        float acc = 0.f;
        #pragma unroll
        for (int n = 0; n < NS; ++n) {
            float dA = __expf(dt * A[n]);
            h[n] = fmaf(dA, h[n], dtu * Bv[n]);
            acc = fmaf(h[n], Cv[n], acc);
        }
        yp[(size_t)i*DI] = fmaf(u, Dv, acc);
    }
}

// ------------- kernel 5: gather + LayerNorm + gate, then tiled GEMM out_proj -------------
#define OP_BM 32
__global__ __launch_bounds__(256) void k_out(const float* __restrict__ oy,
                                             const float* __restrict__ zsilu,
                                             const float* __restrict__ onw,
                                             const float* __restrict__ onb,
                                             const float* __restrict__ opw,
                                             float* __restrict__ out) {
    __shared__ float yv[OP_BM*196];
    __shared__ float wl[96*68];
    int t = threadIdx.x;
    int bl0 = blockIdx.x * OP_BM;
    int lane = t & 63, wv = t >> 6;

    for (int pp = 0; pp < 8; ++pp) {
        int p = wv*8 + pp;
        int bl = bl0 + p;
        int b = bl / LL, l = bl % LL;
        int h = l / WW, w2 = l % WW;
        int i = (w2 & 1) ? (HH-1-h) : h;
        int l0 = i*WW + w2;
        int l1 = ((i & 1) ? (WW-1-w2) : w2)*HH + i;
        size_t base = (size_t)b*KK*LL*DI;
        float yd[3]; float s1 = 0.f, s2 = 0.f;
        #pragma unroll
        for (int j = 0; j < 3; ++j) {
            int c = lane + j*64;
            float v = oy[base + (size_t)(0*LL + l0)*DI + c]
                    + oy[base + (size_t)(1*LL + l1)*DI + c]
                    + oy[base + (size_t)(2*LL + (LL-1-l0))*DI + c]
                    + oy[base + (size_t)(3*LL + (LL-1-l1))*DI + c];
            yd[j] = v; s1 += v; s2 += v*v;
        }
        #pragma unroll
        for (int m = 1; m < 64; m <<= 1) { s1 += __shfl_xor(s1, m); s2 += __shfl_xor(s2, m); }
        float mu  = s1 / DI;
        float var = s2 / DI - mu*mu;
        float ry  = rsqrtf(var + 1e-5f);
        #pragma unroll
        for (int j = 0; j < 3; ++j) {
            int c = lane + j*64;
            float yn = (yd[j] - mu) * ry * onw[c] + onb[c];
            yv[p*196 + c] = yn * zsilu[(size_t)bl*DI + c];
        }
    }

    int pg = t >> 5, eg = t & 31;
    float acc[4][3] = {};
    for (int kc = 0; kc < 3; ++kc) {
        __syncthreads();
        for (int idx = t; idx < 96*64; idx += 256) {
            int r = idx >> 6, c = idx & 63;
            wl[r*68 + c] = opw[r*DI + kc*64 + c];
        }
        __syncthreads();
        #pragma unroll 4
        for (int kk = 0; kk < 64; ++kk) {
            float a[4], bq[3];
            #pragma unroll
            for (int j = 0; j < 4; ++j)  a[j]  = yv[(pg*4+j)*196 + kc*64 + kk];
            #pragma unroll
            for (int jj = 0; jj < 3; ++jj) bq[jj] = wl[(eg*3+jj)*68 + kk];
            #pragma unroll
            for (int j = 0; j < 4; ++j)
                #pragma unroll
                for (int jj = 0; jj < 3; ++jj)
                    acc[j][jj] = fmaf(a[j], bq[jj], acc[j][jj]);
        }
    }
    #pragma unroll
    for (int j = 0; j < 4; ++j) {
        int bl = bl0 + pg*4 + j;
        #pragma unroll
        for (int jj = 0; jj < 3; ++jj)
            out[(size_t)bl*DM + eg*3 + jj] = acc[j][jj];
    }
}

extern "C" void kernel_launch(void* const* d_in, const int* in_sizes, int n_in,
                              void* d_out, int out_size, void* d_ws, size_t ws_size,
                              hipStream_t stream) {
    const float* x      = (const float*)d_in[0];
    const float* ipw    = (const float*)d_in[1];
    const float* convw  = (const float*)d_in[2];
    const float* convb  = (const float*)d_in[3];
    const float* xpw    = (const float*)d_in[4];
    const float* dtw    = (const float*)d_in[5];
    const float* dtb    = (const float*)d_in[6];
    const float* A_logs = (const float*)d_in[7];
    const float* Ds     = (const float*)d_in[8];
    const float* onw    = (const float*)d_in[9];
    const float* onb    = (const float*)d_in[10];
    const float* opw    = (const float*)d_in[11];
    float* out = (float*)d_out;

    float* ws = (float*)d_ws;
    const size_t SZ_BLD  = (size_t)BB*LL*DI;          // 1,204,224
    const size_t SZ_BKLD = (size_t)BB*KK*LL*DI;       // 4,816,896
    const size_t SZ_BKLN = (size_t)BB*KK*LL*NS;       //   401,408
    const size_t SZ_ST   = (size_t)NC*ROWS*NS;        // 2,408,448
    float* xcpre = ws;
    float* zsilu = xcpre + SZ_BLD;
    float* xs0   = zsilu + SZ_BLD;
    float* xs1   = xs0   + SZ_BLD;
    float* delta = xs1   + SZ_BLD;
    float* Bsb   = delta + SZ_BKLD;
    float* Csb   = Bsb   + SZ_BKLN;
    float* oy    = Csb   + SZ_BKLN;
    float* Hin   = oy    + SZ_BKLD;
    float* Hend  = oy;                // alias: dead before oy written (scan2)
    float* P     = oy + SZ_ST;        // alias: 2*SZ_ST == SZ_BKLD, fits exactly

    k_inproj<<<(BB*LL)/IP_BM, 256, 0, stream>>>(x, ipw, xcpre, zsilu);
    k_conv<<<BB*LL, DI, 0, stream>>>(xcpre, convw, convb, xs0, xs1);
    dim3 g3(LL/TL, KK, BB);
    k_proj<<<g3, 256, 0, stream>>>(xs0, xs1, xpw, dtw, dtb, delta, Bsb, Csb);
    dim3 gs(NC, BB*KK);
    k_scan1<<<gs, 192, 0, stream>>>(delta, xs0, xs1, Bsb, A_logs, P, Hend);
    k_scanmid<<<(ROWS*NS)/256, 256, 0, stream>>>(P, Hend, Hin);
    k_scan2<<<gs, 192, 0, stream>>>(delta, xs0, xs1, Bsb, Csb, A_logs, Ds, Hin, oy);
    k_out<<<(BB*LL)/OP_BM, 256, 0, stream>>>(oy, zsilu, onw, onb, opw, out);
}

// Round 6
// 268.186 us; speedup vs baseline: 6.1742x; 1.0204x over previous
//
#include <hip/hip_runtime.h>
#include <hip/hip_bf16.h>

#define BB 2
#define HH 56
#define WW 56
#define LL (HH*WW)          // 3136
#define DM 96
#define DI 192
#define NS 16               // d_state
#define DTR 6
#define KK 4
#define CDBL (DTR + 2*NS)   // 38
#define CS 32               // scan chunk size
#define NC 98               // number of chunks (CS*NC == LL)
#define ROWS (BB*KK*DI)     // 1536 state rows (x NS cols) per chunk

// ---------------- kernel 1: in_proj as tiled GEMM ----------------
#define IP_BM 32
__global__ __launch_bounds__(256) void k_inproj(const float* __restrict__ x,
                                                const float* __restrict__ w,
                                                float* __restrict__ xcpre,
                                                float* __restrict__ zsilu) {
    __shared__ float xl[IP_BM*100];
    __shared__ float wl[64*100];
    int t = threadIdx.x;
    int bl0 = blockIdx.x * IP_BM;
    for (int idx = t; idx < IP_BM*96; idx += 256) {
        int r = idx/96, c = idx%96;
        xl[r*100+c] = x[(bl0+r)*DM + c];
    }
    int pg = t >> 4, eg = t & 15;
    for (int nc = 0; nc < 6; ++nc) {
        __syncthreads();
        for (int idx = t; idx < 64*96; idx += 256) {
            int r = idx/96, c = idx%96;
            wl[r*100+c] = w[(nc*64+r)*DM + c];
        }
        __syncthreads();
        float acc[2][4] = {};
        #pragma unroll 4
        for (int k = 0; k < 96; ++k) {
            float a0 = xl[(pg*2+0)*100+k];
            float a1 = xl[(pg*2+1)*100+k];
            float b0 = wl[(eg*4+0)*100+k];
            float b1 = wl[(eg*4+1)*100+k];
            float b2 = wl[(eg*4+2)*100+k];
            float b3 = wl[(eg*4+3)*100+k];
            acc[0][0] = fmaf(a0,b0,acc[0][0]); acc[0][1] = fmaf(a0,b1,acc[0][1]);
            acc[0][2] = fmaf(a0,b2,acc[0][2]); acc[0][3] = fmaf(a0,b3,acc[0][3]);
            acc[1][0] = fmaf(a1,b0,acc[1][0]); acc[1][1] = fmaf(a1,b1,acc[1][1]);
            acc[1][2] = fmaf(a1,b2,acc[1][2]); acc[1][3] = fmaf(a1,b3,acc[1][3]);
        }
        #pragma unroll
        for (int j = 0; j < 2; ++j) {
            int bl = bl0 + pg*2 + j;
            #pragma unroll
            for (int jj = 0; jj < 4; ++jj) {
                int e = nc*64 + eg*4 + jj;
                float v = acc[j][jj];
                if (e < DI) xcpre[(size_t)bl*DI + e] = v;
                else        zsilu[(size_t)bl*DI + (e-DI)] = v / (1.f + expf(-v));
            }
        }
    }
}

// ------------- kernel 2: depthwise 3x3 conv + bias + silu + scan scatter -------------
__global__ __launch_bounds__(DI) void k_conv(const float* __restrict__ xcpre,
                                             const float* __restrict__ cw,
                                             const float* __restrict__ cb,
                                             float* __restrict__ xs0,
                                             float* __restrict__ xs1) {
    int bl = blockIdx.x;
    int b = bl / LL, l = bl % LL;
    int h = l / WW, w = l % WW;
    int c = threadIdx.x;
    float acc = cb[c];
    #pragma unroll
    for (int dh = -1; dh <= 1; ++dh) {
        int hh = h + dh;
        if (hh < 0 || hh >= HH) continue;
        #pragma unroll
        for (int dw = -1; dw <= 1; ++dw) {
            int ww2 = w + dw;
            if (ww2 < 0 || ww2 >= WW) continue;
            acc = fmaf(xcpre[(b*LL + hh*WW + ww2)*DI + c],
                       cw[c*9 + (dh+1)*3 + (dw+1)], acc);
        }
    }
    float v = acc / (1.f + expf(-acc));   // silu
    int i  = (w & 1) ? (HH-1-h) : h;
    int l0 = i*WW + w;
    int l1 = ((i & 1) ? (WW-1-w) : w)*HH + i;
    xs0[(b*LL + l0)*DI + c] = v;
    xs1[(b*LL + l1)*DI + c] = v;
}

// ------------- kernel 3: x_proj (38x192) + dt_proj (192x6) + softplus -------------
// Phase 1: 2x2 register micro-tile, float4 LDS reads (0.25 ds_read/FMA).
// Phase 2: thread=d, 32 acc in regs, broadcast float4 dblL reads.
#define TL 32
#define XS 196              // padded LDS stride (floats, %4==0; 196%32=4 -> bank spread)
__global__ __launch_bounds__(256) void k_proj(const float* __restrict__ xs0,
                                              const float* __restrict__ xs1,
                                              const float* __restrict__ xpw,   // (K,38,192)
                                              const float* __restrict__ dtw,   // (K,192,6)
                                              const float* __restrict__ dtb,   // (K,192)
                                              float* __restrict__ delta,
                                              float* __restrict__ Bsb,
                                              float* __restrict__ Csb) {
    int tile = blockIdx.x, k = blockIdx.y, b = blockIdx.z;
    int bk = b*KK + k;
    int t = threadIdx.x;
    __shared__ float Wl[CDBL*XS];      // 38 rows
    __shared__ float Xl[TL*XS];        // 32 rows
    __shared__ float dblL[DTR*36];     // 6 rows x 32 (pad 36)

    // stage Wl (float4)
    for (int idx = t; idx < CDBL*48; idx += 256) {
        int r = idx/48, q = idx%48;
        *(float4*)&Wl[r*XS + 4*q] = ((const float4*)(xpw + (size_t)k*CDBL*DI + r*DI))[q];
    }
    // stage Xl (float4)
    const float* src = (k & 1) ? xs1 : xs0;
    const bool rev = (k >= 2);
    for (int idx = t; idx < TL*48; idx += 256) {
        int ll = idx/48, q = idx%48;
        int lg = tile*TL + ll;
        int lp = rev ? (LL-1-lg) : lg;
        *(float4*)&Xl[ll*XS + 4*q] = ((const float4*)(src + (size_t)(b*LL + lp)*DI))[q];
    }
    __syncthreads();

    // phase 1: x_dbl = W_k @ x ; 2c x 2ll micro-tile, 19*16=304 tiles
    for (int tt = t; tt < 304; tt += 256) {
        int cp = tt >> 4, lp = tt & 15;
        int c0 = cp, c1 = cp + 19;
        int ll0 = lp, ll1 = lp + 16;
        float a00=0.f, a01=0.f, a10=0.f, a11=0.f;
        const float4* w0 = (const float4*)&Wl[c0*XS];
        const float4* w1 = (const float4*)&Wl[c1*XS];
        const float4* x0 = (const float4*)&Xl[ll0*XS];
        const float4* x1 = (const float4*)&Xl[ll1*XS];
        #pragma unroll 8
        for (int q = 0; q < 48; ++q) {
            float4 wa = w0[q], wb = w1[q], xa = x0[q], xb = x1[q];
            a00 = fmaf(wa.x,xa.x,a00); a00 = fmaf(wa.y,xa.y,a00);
            a00 = fmaf(wa.z,xa.z,a00); a00 = fmaf(wa.w,xa.w,a00);
            a01 = fmaf(wa.x,xb.x,a01); a01 = fmaf(wa.y,xb.y,a01);
            a01 = fmaf(wa.z,xb.z,a01); a01 = fmaf(wa.w,xb.w,a01);
            a10 = fmaf(wb.x,xa.x,a10); a10 = fmaf(wb.y,xa.y,a10);
            a10 = fmaf(wb.z,xa.z,a10); a10 = fmaf(wb.w,xa.w,a10);
            a11 = fmaf(wb.x,xb.x,a11); a11 = fmaf(wb.y,xb.y,a11);
            a11 = fmaf(wb.z,xb.z,a11); a11 = fmaf(wb.w,xb.w,a11);
        }
        float accs[2][2] = {{a00,a01},{a10,a11}};
        #pragma unroll
        for (int ci = 0; ci < 2; ++ci) {
            int c = ci ? c1 : c0;
            #pragma unroll
            for (int li = 0; li < 2; ++li) {
                int ll = li ? ll1 : ll0;
                int lg = tile*TL + ll;
                float v = accs[ci][li];
                if (c < DTR)           dblL[c*36 + ll] = v;
                else if (c < DTR+NS)   Bsb[((size_t)bk*LL + lg)*NS + (c-DTR)] = v;
                else                   Csb[((size_t)bk*LL + lg)*NS + (c-DTR-NS)] = v;
            }
        }
    }
    __syncthreads();

    // phase 2: delta = softplus(dtw @ dts + bias); thread = d (192 active)
    if (t < DI) {
        int d = t;
        float wr[DTR];
        #pragma unroll
        for (int r = 0; r < DTR; ++r) wr[r] = dtw[((size_t)k*DI + d)*DTR + r];
        float bias = dtb[k*DI + d];
        float acc[TL];
        #pragma unroll
        for (int ll = 0; ll < TL; ++ll) acc[ll] = bias;
        #pragma unroll
        for (int r = 0; r < DTR; ++r) {
            float w = wr[r];
            const float4* db = (const float4*)&dblL[r*36];
            #pragma unroll
            for (int q = 0; q < 8; ++q) {
                float4 v = db[q];   // broadcast across wave
                acc[4*q+0] = fmaf(w, v.x, acc[4*q+0]);
                acc[4*q+1] = fmaf(w, v.y, acc[4*q+1]);
                acc[4*q+2] = fmaf(w, v.z, acc[4*q+2]);
                acc[4*q+3] = fmaf(w, v.w, acc[4*q+3]);
            }
        }
        float* dst = delta + ((size_t)bk*LL + tile*TL)*DI + d;
        #pragma unroll 8
        for (int ll = 0; ll < TL; ++ll) {
            float a = acc[ll];
            float sp = fmaxf(a, 0.f) + log1pf(expf(-fabsf(a)));
            dst[(size_t)ll*DI] = sp;
        }
    }
}

// ------------- kernel 4a: chunked scan pass 1 — thread = d, 16 n-states in regs -------------
// block = 192 threads (all of DI); grid = (NC, B*K)
__global__ __launch_bounds__(192) void k_scan1(const float* __restrict__ delta,
                                               const float* __restrict__ xs0,
                                               const float* __restrict__ xs1,
                                               const float* __restrict__ Bsb,
                                               const float* __restrict__ A_logs,
                                               float* __restrict__ P,     // [c][bk*DI+d][n]
                                               float* __restrict__ Hend) {
    int c = blockIdx.x, bk = blockIdx.y;
    int k = bk & 3, b = bk >> 2;
    int d = threadIdx.x;
    int kd = k*DI + d;
    __shared__ float Bl[CS*NS];
    const float* bsrc = Bsb + ((size_t)bk*LL + c*CS)*NS;
    for (int i = threadIdx.x; i < CS*NS/4; i += 192)
        ((float4*)Bl)[i] = ((const float4*)bsrc)[i];

    float A[NS], h[NS], p[NS];
    #pragma unroll
    for (int q = 0; q < 4; ++q) {
        float4 av = *(const float4*)&A_logs[kd*NS + 4*q];
        A[4*q+0] = -expf(av.x); A[4*q+1] = -expf(av.y);
        A[4*q+2] = -expf(av.z); A[4*q+3] = -expf(av.w);
    }
    #pragma unroll
    for (int n = 0; n < NS; ++n) { h[n] = 0.f; p[n] = 1.f; }
    __syncthreads();

    const bool rev = (k >= 2);
    const float* dp = delta + ((size_t)bk*LL + c*CS)*DI + d;
    const float* up = ((k & 1) ? xs1 : xs0) + (size_t)b*LL*DI + d;
    const int l0 = c*CS;

    #pragma unroll 2
    for (int i = 0; i < CS; ++i) {
        float dt = dp[(size_t)i*DI];
        int lp = rev ? (LL-1-(l0+i)) : (l0+i);
        float u = up[(size_t)lp*DI];
        float dtu = dt * u;
        float Bv[NS];
        #pragma unroll
        for (int q = 0; q < 4; ++q)
            *(float4*)&Bv[4*q] = *(const float4*)&Bl[i*NS + 4*q];
        #pragma unroll
        for (int n = 0; n < NS; ++n) {
            float dA = __expf(dt * A[n]);
            h[n] = fmaf(dA, h[n], dtu * Bv[n]);
            p[n] *= dA;
        }
    }
    size_t obase = ((size_t)c*ROWS + bk*DI + d)*NS;
    #pragma unroll
    for (int q = 0; q < 4; ++q) {
        *(float4*)&P[obase + 4*q]    = make_float4(p[4*q], p[4*q+1], p[4*q+2], p[4*q+3]);
        *(float4*)&Hend[obase + 4*q] = make_float4(h[4*q], h[4*q+1], h[4*q+2], h[4*q+3]);
    }
}

// ------------- kernel 4b: combine chunk states sequentially -------------
__global__ __launch_bounds__(256) void k_scanmid(const float* __restrict__ P,
                                                 const float* __restrict__ Hend,
                                                 float* __restrict__ Hin) {
    int tid = blockIdx.x*256 + threadIdx.x;     // 0 .. ROWS*NS-1
    float h = 0.f;
    for (int c = 0; c < NC; ++c) {
        size_t idx = (size_t)c*(ROWS*NS) + tid;
        Hin[idx] = h;
        h = fmaf(P[idx], h, Hend[idx]);
    }
}

// ------------- kernel 4c: chunked scan pass 2 — rescan with true h_in, emit y -------------
__global__ __launch_bounds__(192) void k_scan2(const float* __restrict__ delta,
                                               const float* __restrict__ xs0,
                                               const float* __restrict__ xs1,
                                               const float* __restrict__ Bsb,
                                               const float* __restrict__ Csb,
                                               const float* __restrict__ A_logs,
                                               const float* __restrict__ Ds,
                                               const float* __restrict__ Hin,
                                               float* __restrict__ oy) {
    int c = blockIdx.x, bk = blockIdx.y;
    int k = bk & 3, b = bk >> 2;
    int d = threadIdx.x;
    int kd = k*DI + d;
    __shared__ float Bl[CS*NS];
    __shared__ float Cl[CS*NS];
    const float* bsrc = Bsb + ((size_t)bk*LL + c*CS)*NS;
    const float* csrc = Csb + ((size_t)bk*LL + c*CS)*NS;
    for (int i = threadIdx.x; i < CS*NS/4; i += 192) {
        ((float4*)Bl)[i] = ((const float4*)bsrc)[i];
        ((float4*)Cl)[i] = ((const float4*)csrc)[i];
    }

    float A[NS], h[NS];
    #pragma unroll
    for (int q = 0; q < 4; ++q) {
        float4 av = *(const float4*)&A_logs[kd*NS + 4*q];
        A[4*q+0] = -expf(av.x); A[4*q+1] = -expf(av.y);
        A[4*q+2] = -expf(av.z); A[4*q+3] = -expf(av.w);
    }
    size_t ibase = ((size_t)c*ROWS + bk*DI + d)*NS;
    #pragma unroll
    for (int q = 0; q < 4; ++q) {
        float4 hv = *(const float4*)&Hin[ibase + 4*q];
        h[4*q+0] = hv.x; h[4*q+1] = hv.y; h[4*q+2] = hv.z; h[4*q+3] = hv.w;
    }
    const float Dv = Ds[kd];
    __syncthreads();

    const bool rev = (k >= 2);
    const float* dp = delta + ((size_t)bk*LL + c*CS)*DI + d;
    const float* up = ((k & 1) ? xs1 : xs0) + (size_t)b*LL*DI + d;
    float* yp = oy + ((size_t)bk*LL + c*CS)*DI + d;
    const int l0 = c*CS;

    #pragma unroll 2
    for (int i = 0; i < CS; ++i) {
        float dt = dp[(size_t)i*DI];
        int lp = rev ? (LL-1-(l0+i)) : (l0+i);
        float u = up[(size_t)lp*DI];
        float dtu = dt * u;
        float Bv[NS], Cv[NS];
        #pragma unroll
        for (int q = 0; q < 4; ++q) {
            *(float4*)&Bv[4*q] = *(const float4*)&Bl[i*NS + 4*q];
            *(float4*)&Cv[4*q] = *(const float4*)&Cl[i*NS + 4*q];
        }
        float acc = 0.f;
        #pragma unroll
        for (int n = 0; n < NS; ++n) {
            float dA = __expf(dt * A[n]);
            h[n] = fmaf(dA, h[n], dtu * Bv[n]);
            acc = fmaf(h[n], Cv[n], acc);
        }
        yp[(size_t)i*DI] = fmaf(u, Dv, acc);
    }
}

// ------------- kernel 5: gather + LayerNorm + gate, then tiled GEMM out_proj -------------
#define OP_BM 32
__global__ __launch_bounds__(256) void k_out(const float* __restrict__ oy,
                                             const float* __restrict__ zsilu,
                                             const float* __restrict__ onw,
                                             const float* __restrict__ onb,
                                             const float* __restrict__ opw,
                                             float* __restrict__ out) {
    __shared__ float yv[OP_BM*196];
    __shared__ float wl[96*68];
    int t = threadIdx.x;
    int bl0 = blockIdx.x * OP_BM;
    int lane = t & 63, wv = t >> 6;

    for (int pp = 0; pp < 8; ++pp) {
        int p = wv*8 + pp;
        int bl = bl0 + p;
        int b = bl / LL, l = bl % LL;
        int h = l / WW, w2 = l % WW;
        int i = (w2 & 1) ? (HH-1-h) : h;
        int l0 = i*WW + w2;
        int l1 = ((i & 1) ? (WW-1-w2) : w2)*HH + i;
        size_t base = (size_t)b*KK*LL*DI;
        float yd[3]; float s1 = 0.f, s2 = 0.f;
        #pragma unroll
        for (int j = 0; j < 3; ++j) {
            int c = lane + j*64;
            float v = oy[base + (size_t)(0*LL + l0)*DI + c]
                    + oy[base + (size_t)(1*LL + l1)*DI + c]
                    + oy[base + (size_t)(2*LL + (LL-1-l0))*DI + c]
                    + oy[base + (size_t)(3*LL + (LL-1-l1))*DI + c];
            yd[j] = v; s1 += v; s2 += v*v;
        }
        #pragma unroll
        for (int m = 1; m < 64; m <<= 1) { s1 += __shfl_xor(s1, m); s2 += __shfl_xor(s2, m); }
        float mu  = s1 / DI;
        float var = s2 / DI - mu*mu;
        float ry  = rsqrtf(var + 1e-5f);
        #pragma unroll
        for (int j = 0; j < 3; ++j) {
            int c = lane + j*64;
            float yn = (yd[j] - mu) * ry * onw[c] + onb[c];
            yv[p*196 + c] = yn * zsilu[(size_t)bl*DI + c];
        }
    }

    int pg = t >> 5, eg = t & 31;
    float acc[4][3] = {};
    for (int kc = 0; kc < 3; ++kc) {
        __syncthreads();
        for (int idx = t; idx < 96*64; idx += 256) {
            int r = idx >> 6, c = idx & 63;
            wl[r*68 + c] = opw[r*DI + kc*64 + c];
        }
        __syncthreads();
        #pragma unroll 4
        for (int kk = 0; kk < 64; ++kk) {
            float a[4], bq[3];
            #pragma unroll
            for (int j = 0; j < 4; ++j)  a[j]  = yv[(pg*4+j)*196 + kc*64 + kk];
            #pragma unroll
            for (int jj = 0; jj < 3; ++jj) bq[jj] = wl[(eg*3+jj)*68 + kk];
            #pragma unroll
            for (int j = 0; j < 4; ++j)
                #pragma unroll
                for (int jj = 0; jj < 3; ++jj)
                    acc[j][jj] = fmaf(a[j], bq[jj], acc[j][jj]);
        }
    }
    #pragma unroll
    for (int j = 0; j < 4; ++j) {
        int bl = bl0 + pg*4 + j;
        #pragma unroll
        for (int jj = 0; jj < 3; ++jj)
            out[(size_t)bl*DM + eg*3 + jj] = acc[j][jj];
    }
}

extern "C" void kernel_launch(void* const* d_in, const int* in_sizes, int n_in,
                              void* d_out, int out_size, void* d_ws, size_t ws_size,
                              hipStream_t stream) {
    const float* x      = (const float*)d_in[0];
    const float* ipw    = (const float*)d_in[1];
    const float* convw  = (const float*)d_in[2];
    const float* convb  = (const float*)d_in[3];
    const float* xpw    = (const float*)d_in[4];
    const float* dtw    = (const float*)d_in[5];
    const float* dtb    = (const float*)d_in[6];
    const float* A_logs = (const float*)d_in[7];
    const float* Ds     = (const float*)d_in[8];
    const float* onw    = (const float*)d_in[9];
    const float* onb    = (const float*)d_in[10];
    const float* opw    = (const float*)d_in[11];
    float* out = (float*)d_out;

    float* ws = (float*)d_ws;
    const size_t SZ_BLD  = (size_t)BB*LL*DI;          // 1,204,224
    const size_t SZ_BKLD = (size_t)BB*KK*LL*DI;       // 4,816,896
    const size_t SZ_BKLN = (size_t)BB*KK*LL*NS;       //   401,408
    const size_t SZ_ST   = (size_t)NC*ROWS*NS;        // 2,408,448
    float* xcpre = ws;
    float* zsilu = xcpre + SZ_BLD;
    float* xs0   = zsilu + SZ_BLD;
    float* xs1   = xs0   + SZ_BLD;
    float* delta = xs1   + SZ_BLD;
    float* Bsb   = delta + SZ_BKLD;
    float* Csb   = Bsb   + SZ_BKLN;
    float* oy    = Csb   + SZ_BKLN;
    float* Hin   = oy    + SZ_BKLD;
    float* Hend  = oy;                // alias: dead before oy written (scan2)
    float* P     = oy + SZ_ST;        // alias: 2*SZ_ST == SZ_BKLD, fits exactly

    k_inproj<<<(BB*LL)/IP_BM, 256, 0, stream>>>(x, ipw, xcpre, zsilu);
    k_conv<<<BB*LL, DI, 0, stream>>>(xcpre, convw, convb, xs0, xs1);
    dim3 g3(LL/TL, KK, BB);
    k_proj<<<g3, 256, 0, stream>>>(xs0, xs1, xpw, dtw, dtb, delta, Bsb, Csb);
    dim3 gs(NC, BB*KK);
    k_scan1<<<gs, 192, 0, stream>>>(delta, xs0, xs1, Bsb, A_logs, P, Hend);
    k_scanmid<<<(ROWS*NS)/256, 256, 0, stream>>>(P, Hend, Hin);
    k_scan2<<<gs, 192, 0, stream>>>(delta, xs0, xs1, Bsb, Csb, A_logs, Ds, Hin, oy);
    k_out<<<(BB*LL)/OP_BM, 256, 0, stream>>>(oy, zsilu, onw, onb, opw, out);
}

// Round 7
// 259.019 us; speedup vs baseline: 6.3927x; 1.0354x over previous
//
#include <hip/hip_runtime.h>
#include <hip/hip_bf16.h>

#define BB 2
#define HH 56
#define WW 56
#define LL (HH*WW)          // 3136
#define DM 96
#define DI 192
#define NS 16               // d_state
#define DTR 6
#define KK 4
#define CDBL (DTR + 2*NS)   // 38
#define CS 32               // scan chunk size
#define NC 98               // number of chunks (CS*NC == LL)
#define ROWS (BB*KK*DI)     // 1536 state rows (x NS cols) per chunk

// ---------------- kernel 1: in_proj as tiled GEMM ----------------
#define IP_BM 32
__global__ __launch_bounds__(256) void k_inproj(const float* __restrict__ x,
                                                const float* __restrict__ w,
                                                float* __restrict__ xcpre,
                                                float* __restrict__ zsilu) {
    __shared__ float xl[IP_BM*100];
    __shared__ float wl[64*100];
    int t = threadIdx.x;
    int bl0 = blockIdx.x * IP_BM;
    for (int idx = t; idx < IP_BM*96; idx += 256) {
        int r = idx/96, c = idx%96;
        xl[r*100+c] = x[(bl0+r)*DM + c];
    }
    int pg = t >> 4, eg = t & 15;
    for (int nc = 0; nc < 6; ++nc) {
        __syncthreads();
        for (int idx = t; idx < 64*96; idx += 256) {
            int r = idx/96, c = idx%96;
            wl[r*100+c] = w[(nc*64+r)*DM + c];
        }
        __syncthreads();
        float acc[2][4] = {};
        #pragma unroll 4
        for (int k = 0; k < 96; ++k) {
            float a0 = xl[(pg*2+0)*100+k];
            float a1 = xl[(pg*2+1)*100+k];
            float b0 = wl[(eg*4+0)*100+k];
            float b1 = wl[(eg*4+1)*100+k];
            float b2 = wl[(eg*4+2)*100+k];
            float b3 = wl[(eg*4+3)*100+k];
            acc[0][0] = fmaf(a0,b0,acc[0][0]); acc[0][1] = fmaf(a0,b1,acc[0][1]);
            acc[0][2] = fmaf(a0,b2,acc[0][2]); acc[0][3] = fmaf(a0,b3,acc[0][3]);
            acc[1][0] = fmaf(a1,b0,acc[1][0]); acc[1][1] = fmaf(a1,b1,acc[1][1]);
            acc[1][2] = fmaf(a1,b2,acc[1][2]); acc[1][3] = fmaf(a1,b3,acc[1][3]);
        }
        #pragma unroll
        for (int j = 0; j < 2; ++j) {
            int bl = bl0 + pg*2 + j;
            #pragma unroll
            for (int jj = 0; jj < 4; ++jj) {
                int e = nc*64 + eg*4 + jj;
                float v = acc[j][jj];
                if (e < DI) xcpre[(size_t)bl*DI + e] = v;
                else        zsilu[(size_t)bl*DI + (e-DI)] = v / (1.f + expf(-v));
            }
        }
    }
}

// ------------- kernel 2: depthwise 3x3 conv + bias + silu + scan scatter -------------
__global__ __launch_bounds__(DI) void k_conv(const float* __restrict__ xcpre,
                                             const float* __restrict__ cw,
                                             const float* __restrict__ cb,
                                             float* __restrict__ xs0,
                                             float* __restrict__ xs1) {
    int bl = blockIdx.x;
    int b = bl / LL, l = bl % LL;
    int h = l / WW, w = l % WW;
    int c = threadIdx.x;
    float acc = cb[c];
    #pragma unroll
    for (int dh = -1; dh <= 1; ++dh) {
        int hh = h + dh;
        if (hh < 0 || hh >= HH) continue;
        #pragma unroll
        for (int dw = -1; dw <= 1; ++dw) {
            int ww2 = w + dw;
            if (ww2 < 0 || ww2 >= WW) continue;
            acc = fmaf(xcpre[(b*LL + hh*WW + ww2)*DI + c],
                       cw[c*9 + (dh+1)*3 + (dw+1)], acc);
        }
    }
    float v = acc / (1.f + expf(-acc));   // silu
    int i  = (w & 1) ? (HH-1-h) : h;
    int l0 = i*WW + w;
    int l1 = ((i & 1) ? (WW-1-w) : w)*HH + i;
    xs0[(b*LL + l0)*DI + c] = v;
    xs1[(b*LL + l1)*DI + c] = v;
}

// ------------- kernel 3: x_proj + dt_proj + softplus (occupancy-tuned) -------------
// TL=64 positions/block; K staged in 4 chunks of 48 ch (LDS ~22.5KB -> 5+ blocks/CU).
// Phase 1: 3c x 4ll micro-tile, ONE pass (208 of 256 threads).
// Phase 2: all 256 threads, 48 outputs each, static-unrolled register cache.
#define TL 64
#define KCH 48
#define NKC 4
#define XSTR 52
#define WSTR 52
__global__ __launch_bounds__(256) void k_proj(const float* __restrict__ xs0,
                                              const float* __restrict__ xs1,
                                              const float* __restrict__ xpw,   // (K,38,192)
                                              const float* __restrict__ dtw,   // (K,192,6)
                                              const float* __restrict__ dtb,   // (K,192)
                                              float* __restrict__ delta,
                                              float* __restrict__ Bsb,
                                              float* __restrict__ Csb) {
    int tile = blockIdx.x, k = blockIdx.y, b = blockIdx.z;
    int bk = b*KK + k;
    int t = threadIdx.x;
    __shared__ float Xl[TL*XSTR];      // 64 x 48-chunk, stride 52
    __shared__ float Wl[39*WSTR];      // 38 rows + 1 junk (c=38), stride 52
    __shared__ float dblL[DTR*68];     // dt rows, 64 + pad

    const float* src = (k & 1) ? xs1 : xs0;
    const bool rev = (k >= 2);
    int cp = t >> 4, lp = t & 15;      // cp 0..15 (only <13 compute), lp 0..15

    float acc[3][4] = {};
    for (int kc = 0; kc < NKC; ++kc) {
        __syncthreads();
        // stage Wl (39 rows x 12 float4; row 38 zero)
        for (int idx = t; idx < 39*12; idx += 256) {
            int r = idx/12, q = idx%12;
            float4 v = (r < CDBL)
                ? ((const float4*)(xpw + (size_t)k*CDBL*DI + (size_t)r*DI + kc*KCH))[q]
                : make_float4(0.f,0.f,0.f,0.f);
            *(float4*)&Wl[r*WSTR + 4*q] = v;
        }
        // stage Xl (64 rows x 12 float4)
        for (int idx = t; idx < TL*12; idx += 256) {
            int ll = idx/12, q = idx%12;
            int lg = tile*TL + ll;
            int lpos = rev ? (LL-1-lg) : lg;
            *(float4*)&Xl[ll*XSTR + 4*q] =
                ((const float4*)(src + (size_t)(b*LL + lpos)*DI + kc*KCH))[q];
        }
        __syncthreads();
        if (cp < 13) {
            const float4* w0 = (const float4*)&Wl[(3*cp+0)*WSTR];
            const float4* w1 = (const float4*)&Wl[(3*cp+1)*WSTR];
            const float4* w2 = (const float4*)&Wl[(3*cp+2)*WSTR];
            const float4* x0 = (const float4*)&Xl[(lp    )*XSTR];
            const float4* x1 = (const float4*)&Xl[(lp+16)*XSTR];
            const float4* x2 = (const float4*)&Xl[(lp+32)*XSTR];
            const float4* x3 = (const float4*)&Xl[(lp+48)*XSTR];
            #pragma unroll
            for (int q = 0; q < 12; ++q) {
                float4 wa = w0[q], wb = w1[q], wc = w2[q];
                float4 xa = x0[q], xb = x1[q], xc = x2[q], xd = x3[q];
                acc[0][0]=fmaf(wa.x,xa.x,acc[0][0]); acc[0][0]=fmaf(wa.y,xa.y,acc[0][0]);
                acc[0][0]=fmaf(wa.z,xa.z,acc[0][0]); acc[0][0]=fmaf(wa.w,xa.w,acc[0][0]);
                acc[0][1]=fmaf(wa.x,xb.x,acc[0][1]); acc[0][1]=fmaf(wa.y,xb.y,acc[0][1]);
                acc[0][1]=fmaf(wa.z,xb.z,acc[0][1]); acc[0][1]=fmaf(wa.w,xb.w,acc[0][1]);
                acc[0][2]=fmaf(wa.x,xc.x,acc[0][2]); acc[0][2]=fmaf(wa.y,xc.y,acc[0][2]);
                acc[0][2]=fmaf(wa.z,xc.z,acc[0][2]); acc[0][2]=fmaf(wa.w,xc.w,acc[0][2]);
                acc[0][3]=fmaf(wa.x,xd.x,acc[0][3]); acc[0][3]=fmaf(wa.y,xd.y,acc[0][3]);
                acc[0][3]=fmaf(wa.z,xd.z,acc[0][3]); acc[0][3]=fmaf(wa.w,xd.w,acc[0][3]);
                acc[1][0]=fmaf(wb.x,xa.x,acc[1][0]); acc[1][0]=fmaf(wb.y,xa.y,acc[1][0]);
                acc[1][0]=fmaf(wb.z,xa.z,acc[1][0]); acc[1][0]=fmaf(wb.w,xa.w,acc[1][0]);
                acc[1][1]=fmaf(wb.x,xb.x,acc[1][1]); acc[1][1]=fmaf(wb.y,xb.y,acc[1][1]);
                acc[1][1]=fmaf(wb.z,xb.z,acc[1][1]); acc[1][1]=fmaf(wb.w,xb.w,acc[1][1]);
                acc[1][2]=fmaf(wb.x,xc.x,acc[1][2]); acc[1][2]=fmaf(wb.y,xc.y,acc[1][2]);
                acc[1][2]=fmaf(wb.z,xc.z,acc[1][2]); acc[1][2]=fmaf(wb.w,xc.w,acc[1][2]);
                acc[1][3]=fmaf(wb.x,xd.x,acc[1][3]); acc[1][3]=fmaf(wb.y,xd.y,acc[1][3]);
                acc[1][3]=fmaf(wb.z,xd.z,acc[1][3]); acc[1][3]=fmaf(wb.w,xd.w,acc[1][3]);
                acc[2][0]=fmaf(wc.x,xa.x,acc[2][0]); acc[2][0]=fmaf(wc.y,xa.y,acc[2][0]);
                acc[2][0]=fmaf(wc.z,xa.z,acc[2][0]); acc[2][0]=fmaf(wc.w,xa.w,acc[2][0]);
                acc[2][1]=fmaf(wc.x,xb.x,acc[2][1]); acc[2][1]=fmaf(wc.y,xb.y,acc[2][1]);
                acc[2][1]=fmaf(wc.z,xb.z,acc[2][1]); acc[2][1]=fmaf(wc.w,xb.w,acc[2][1]);
                acc[2][2]=fmaf(wc.x,xc.x,acc[2][2]); acc[2][2]=fmaf(wc.y,xc.y,acc[2][2]);
                acc[2][2]=fmaf(wc.z,xc.z,acc[2][2]); acc[2][2]=fmaf(wc.w,xc.w,acc[2][2]);
                acc[2][3]=fmaf(wc.x,xd.x,acc[2][3]); acc[2][3]=fmaf(wc.y,xd.y,acc[2][3]);
                acc[2][3]=fmaf(wc.z,xd.z,acc[2][3]); acc[2][3]=fmaf(wc.w,xd.w,acc[2][3]);
            }
        }
    }
    // scatter outputs
    if (cp < 13) {
        #pragma unroll
        for (int ci = 0; ci < 3; ++ci) {
            int c = 3*cp + ci;
            if (c < CDBL) {
                #pragma unroll
                for (int li = 0; li < 4; ++li) {
                    int ll = lp + 16*li;
                    int lg = tile*TL + ll;
                    float v = acc[ci][li];
                    if (c < DTR)          dblL[c*68 + ll] = v;
                    else if (c < DTR+NS)  Bsb[((size_t)bk*LL + lg)*NS + (c-DTR)] = v;
                    else                  Csb[((size_t)bk*LL + lg)*NS + (c-DTR-NS)] = v;
                }
            }
        }
    }
    __syncthreads();

    // phase 2: delta (64 x 192 outputs, all 256 threads, 48 each)
    float wr0[DTR], wr1[DTR], wr2[DTR], bb0, bb1, bb2;
    {
        int d0 = t % DI, d1 = (t+64) % DI, d2 = (t+128) % DI;
        #pragma unroll
        for (int r = 0; r < DTR; ++r) {
            wr0[r] = dtw[((size_t)k*DI + d0)*DTR + r];
            wr1[r] = dtw[((size_t)k*DI + d1)*DTR + r];
            wr2[r] = dtw[((size_t)k*DI + d2)*DTR + r];
        }
        bb0 = dtb[k*DI + d0]; bb1 = dtb[k*DI + d1]; bb2 = dtb[k*DI + d2];
    }
    float* dbase = delta + ((size_t)bk*LL + (size_t)tile*TL)*DI;
    for (int j3 = 0; j3 < 16; ++j3) {
        #pragma unroll
        for (int jj = 0; jj < 3; ++jj) {
            int j = j3*3 + jj;
            int idx = t + 256*j;
            int d = idx % DI;
            int ll = idx / DI;
            float a = (jj == 0) ? bb0 : (jj == 1) ? bb1 : bb2;
            const float* wrp = (jj == 0) ? wr0 : (jj == 1) ? wr1 : wr2;
            #pragma unroll
            for (int r = 0; r < DTR; ++r) a = fmaf(wrp[r], dblL[r*68 + ll], a);
            float sp = fmaxf(a, 0.f) + log1pf(expf(-fabsf(a)));
            dbase[(size_t)ll*DI + d] = sp;
        }
    }
}

// ------------- kernel 4a: chunked scan pass 1 — thread = d, 16 n-states in regs -------------
__global__ __launch_bounds__(192) void k_scan1(const float* __restrict__ delta,
                                               const float* __restrict__ xs0,
                                               const float* __restrict__ xs1,
                                               const float* __restrict__ Bsb,
                                               const float* __restrict__ A_logs,
                                               float* __restrict__ P,     // [c][bk*DI+d][n]
                                               float* __restrict__ Hend) {
    int c = blockIdx.x, bk = blockIdx.y;
    int k = bk & 3, b = bk >> 2;
    int d = threadIdx.x;
    int kd = k*DI + d;
    __shared__ float Bl[CS*NS];
    const float* bsrc = Bsb + ((size_t)bk*LL + c*CS)*NS;
    for (int i = threadIdx.x; i < CS*NS/4; i += 192)
        ((float4*)Bl)[i] = ((const float4*)bsrc)[i];

    float A[NS], h[NS], p[NS];
    #pragma unroll
    for (int q = 0; q < 4; ++q) {
        float4 av = *(const float4*)&A_logs[kd*NS + 4*q];
        A[4*q+0] = -expf(av.x); A[4*q+1] = -expf(av.y);
        A[4*q+2] = -expf(av.z); A[4*q+3] = -expf(av.w);
    }
    #pragma unroll
    for (int n = 0; n < NS; ++n) { h[n] = 0.f; p[n] = 1.f; }
    __syncthreads();

    const bool rev = (k >= 2);
    const float* dp = delta + ((size_t)bk*LL + c*CS)*DI + d;
    const float* up = ((k & 1) ? xs1 : xs0) + (size_t)b*LL*DI + d;
    const int l0 = c*CS;

    #pragma unroll 2
    for (int i = 0; i < CS; ++i) {
        float dt = dp[(size_t)i*DI];
        int lp = rev ? (LL-1-(l0+i)) : (l0+i);
        float u = up[(size_t)lp*DI];
        float dtu = dt * u;
        float Bv[NS];
        #pragma unroll
        for (int q = 0; q < 4; ++q)
            *(float4*)&Bv[4*q] = *(const float4*)&Bl[i*NS + 4*q];
        #pragma unroll
        for (int n = 0; n < NS; ++n) {
            float dA = __expf(dt * A[n]);
            h[n] = fmaf(dA, h[n], dtu * Bv[n]);
            p[n] *= dA;
        }
    }
    size_t obase = ((size_t)c*ROWS + bk*DI + d)*NS;
    #pragma unroll
    for (int q = 0; q < 4; ++q) {
        *(float4*)&P[obase + 4*q]    = make_float4(p[4*q], p[4*q+1], p[4*q+2], p[4*q+3]);
        *(float4*)&Hend[obase + 4*q] = make_float4(h[4*q], h[4*q+1], h[4*q+2], h[4*q+3]);
    }
}

// ------------- kernel 4b: combine chunk states sequentially -------------
__global__ __launch_bounds__(256) void k_scanmid(const float* __restrict__ P,
                                                 const float* __restrict__ Hend,
                                                 float* __restrict__ Hin) {
    int tid = blockIdx.x*256 + threadIdx.x;     // 0 .. ROWS*NS-1
    float h = 0.f;
    for (int c = 0; c < NC; ++c) {
        size_t idx = (size_t)c*(ROWS*NS) + tid;
        Hin[idx] = h;
        h = fmaf(P[idx], h, Hend[idx]);
    }
}

// ------------- kernel 4c: chunked scan pass 2 — rescan with true h_in, emit y -------------
__global__ __launch_bounds__(192) void k_scan2(const float* __restrict__ delta,
                                               const float* __restrict__ xs0,
                                               const float* __restrict__ xs1,
                                               const float* __restrict__ Bsb,
                                               const float* __restrict__ Csb,
                                               const float* __restrict__ A_logs,
                                               const float* __restrict__ Ds,
                                               const float* __restrict__ Hin,
                                               float* __restrict__ oy) {
    int c = blockIdx.x, bk = blockIdx.y;
    int k = bk & 3, b = bk >> 2;
    int d = threadIdx.x;
    int kd = k*DI + d;
    __shared__ float Bl[CS*NS];
    __shared__ float Cl[CS*NS];
    const float* bsrc = Bsb + ((size_t)bk*LL + c*CS)*NS;
    const float* csrc = Csb + ((size_t)bk*LL + c*CS)*NS;
    for (int i = threadIdx.x; i < CS*NS/4; i += 192) {
        ((float4*)Bl)[i] = ((const float4*)bsrc)[i];
        ((float4*)Cl)[i] = ((const float4*)csrc)[i];
    }

    float A[NS], h[NS];
    #pragma unroll
    for (int q = 0; q < 4; ++q) {
        float4 av = *(const float4*)&A_logs[kd*NS + 4*q];
        A[4*q+0] = -expf(av.x); A[4*q+1] = -expf(av.y);
        A[4*q+2] = -expf(av.z); A[4*q+3] = -expf(av.w);
    }
    size_t ibase = ((size_t)c*ROWS + bk*DI + d)*NS;
    #pragma unroll
    for (int q = 0; q < 4; ++q) {
        float4 hv = *(const float4*)&Hin[ibase + 4*q];
        h[4*q+0] = hv.x; h[4*q+1] = hv.y; h[4*q+2] = hv.z; h[4*q+3] = hv.w;
    }
    const float Dv = Ds[kd];
    __syncthreads();

    const bool rev = (k >= 2);
    const float* dp = delta + ((size_t)bk*LL + c*CS)*DI + d;
    const float* up = ((k & 1) ? xs1 : xs0) + (size_t)b*LL*DI + d;
    float* yp = oy + ((size_t)bk*LL + c*CS)*DI + d;
    const int l0 = c*CS;

    #pragma unroll 2
    for (int i = 0; i < CS; ++i) {
        float dt = dp[(size_t)i*DI];
        int lp = rev ? (LL-1-(l0+i)) : (l0+i);
        float u = up[(size_t)lp*DI];
        float dtu = dt * u;
        float Bv[NS], Cv[NS];
        #pragma unroll
        for (int q = 0; q < 4; ++q) {
            *(float4*)&Bv[4*q] = *(const float4*)&Bl[i*NS + 4*q];
            *(float4*)&Cv[4*q] = *(const float4*)&Cl[i*NS + 4*q];
        }
        float acc = 0.f;
        #pragma unroll
        for (int n = 0; n < NS; ++n) {
            float dA = __expf(dt * A[n]);
            h[n] = fmaf(dA, h[n], dtu * Bv[n]);
            acc = fmaf(h[n], Cv[n], acc);
        }
        yp[(size_t)i*DI] = fmaf(u, Dv, acc);
    }
}

// ------------- kernel 5: gather + LayerNorm + gate, then tiled GEMM out_proj -------------
#define OP_BM 32
__global__ __launch_bounds__(256) void k_out(const float* __restrict__ oy,
                                             const float* __restrict__ zsilu,
                                             const float* __restrict__ onw,
                                             const float* __restrict__ onb,
                                             const float* __restrict__ opw,
                                             float* __restrict__ out) {
    __shared__ float yv[OP_BM*196];
    __shared__ float wl[96*68];
    int t = threadIdx.x;
    int bl0 = blockIdx.x * OP_BM;
    int lane = t & 63, wv = t >> 6;

    for (int pp = 0; pp < 8; ++pp) {
        int p = wv*8 + pp;
        int bl = bl0 + p;
        int b = bl / LL, l = bl % LL;
        int h = l / WW, w2 = l % WW;
        int i = (w2 & 1) ? (HH-1-h) : h;
        int l0 = i*WW + w2;
        int l1 = ((i & 1) ? (WW-1-w2) : w2)*HH + i;
        size_t base = (size_t)b*KK*LL*DI;
        float yd[3]; float s1 = 0.f, s2 = 0.f;
        #pragma unroll
        for (int j = 0; j < 3; ++j) {
            int c = lane + j*64;
            float v = oy[base + (size_t)(0*LL + l0)*DI + c]
                    + oy[base + (size_t)(1*LL + l1)*DI + c]
                    + oy[base + (size_t)(2*LL + (LL-1-l0))*DI + c]
                    + oy[base + (size_t)(3*LL + (LL-1-l1))*DI + c];
            yd[j] = v; s1 += v; s2 += v*v;
        }
        #pragma unroll
        for (int m = 1; m < 64; m <<= 1) { s1 += __shfl_xor(s1, m); s2 += __shfl_xor(s2, m); }
        float mu  = s1 / DI;
        float var = s2 / DI - mu*mu;
        float ry  = rsqrtf(var + 1e-5f);
        #pragma unroll
        for (int j = 0; j < 3; ++j) {
            int c = lane + j*64;
            float yn = (yd[j] - mu) * ry * onw[c] + onb[c];
            yv[p*196 + c] = yn * zsilu[(size_t)bl*DI + c];
        }
    }

    int pg = t >> 5, eg = t & 31;
    float acc[4][3] = {};
    for (int kc = 0; kc < 3; ++kc) {
        __syncthreads();
        for (int idx = t; idx < 96*64; idx += 256) {
            int r = idx >> 6, c = idx & 63;
            wl[r*68 + c] = opw[r*DI + kc*64 + c];
        }
        __syncthreads();
        #pragma unroll 4
        for (int kk = 0; kk < 64; ++kk) {
            float a[4], bq[3];
            #pragma unroll
            for (int j = 0; j < 4; ++j)  a[j]  = yv[(pg*4+j)*196 + kc*64 + kk];
            #pragma unroll
            for (int jj = 0; jj < 3; ++jj) bq[jj] = wl[(eg*3+jj)*68 + kk];
            #pragma unroll
            for (int j = 0; j < 4; ++j)
                #pragma unroll
                for (int jj = 0; jj < 3; ++jj)
                    acc[j][jj] = fmaf(a[j], bq[jj], acc[j][jj]);
        }
    }
    #pragma unroll
    for (int j = 0; j < 4; ++j) {
        int bl = bl0 + pg*4 + j;
        #pragma unroll
        for (int jj = 0; jj < 3; ++jj)
            out[(size_t)bl*DM + eg*3 + jj] = acc[j][jj];
    }
}

extern "C" void kernel_launch(void* const* d_in, const int* in_sizes, int n_in,
                              void* d_out, int out_size, void* d_ws, size_t ws_size,
                              hipStream_t stream) {
    const float* x      = (const float*)d_in[0];
    const float* ipw    = (const float*)d_in[1];
    const float* convw  = (const float*)d_in[2];
    const float* convb  = (const float*)d_in[3];
    const float* xpw    = (const float*)d_in[4];
    const float* dtw    = (const float*)d_in[5];
    const float* dtb    = (const float*)d_in[6];
    const float* A_logs = (const float*)d_in[7];
    const float* Ds     = (const float*)d_in[8];
    const float* onw    = (const float*)d_in[9];
    const float* onb    = (const float*)d_in[10];
    const float* opw    = (const float*)d_in[11];
    float* out = (float*)d_out;

    float* ws = (float*)d_ws;
    const size_t SZ_BLD  = (size_t)BB*LL*DI;          // 1,204,224
    const size_t SZ_BKLD = (size_t)BB*KK*LL*DI;       // 4,816,896
    const size_t SZ_BKLN = (size_t)BB*KK*LL*NS;       //   401,408
    const size_t SZ_ST   = (size_t)NC*ROWS*NS;        // 2,408,448
    float* xcpre = ws;
    float* zsilu = xcpre + SZ_BLD;
    float* xs0   = zsilu + SZ_BLD;
    float* xs1   = xs0   + SZ_BLD;
    float* delta = xs1   + SZ_BLD;
    float* Bsb   = delta + SZ_BKLD;
    float* Csb   = Bsb   + SZ_BKLN;
    float* oy    = Csb   + SZ_BKLN;
    float* Hin   = oy    + SZ_BKLD;
    float* Hend  = oy;                // alias: dead before oy written (scan2)
    float* P     = oy + SZ_ST;        // alias: 2*SZ_ST == SZ_BKLD, fits exactly

    k_inproj<<<(BB*LL)/IP_BM, 256, 0, stream>>>(x, ipw, xcpre, zsilu);
    k_conv<<<BB*LL, DI, 0, stream>>>(xcpre, convw, convb, xs0, xs1);
    dim3 g3(LL/TL, KK, BB);
    k_proj<<<g3, 256, 0, stream>>>(xs0, xs1, xpw, dtw, dtb, delta, Bsb, Csb);
    dim3 gs(NC, BB*KK);
    k_scan1<<<gs, 192, 0, stream>>>(delta, xs0, xs1, Bsb, A_logs, P, Hend);
    k_scanmid<<<(ROWS*NS)/256, 256, 0, stream>>>(P, Hend, Hin);
    k_scan2<<<gs, 192, 0, stream>>>(delta, xs0, xs1, Bsb, Csb, A_logs, Ds, Hin, oy);
    k_out<<<(BB*LL)/OP_BM, 256, 0, stream>>>(oy, zsilu, onw, onb, opw, out);
}